// Round 5
// baseline (126.026 us; speedup 1.0000x reference)
//
#include <hip/hip_runtime.h>
#include <math.h>

#define B_ 4
#define S_ 2048
#define D_ 512
#define H_ 8
#define DH_ 64
#define BH_ (B_*H_)
#define SCALE 0.1803368801111243f   // log2(e)/sqrt(64)

typedef __attribute__((ext_vector_type(4)))  float f32x4;
typedef __attribute__((ext_vector_type(16))) float f32x16;
typedef __attribute__((ext_vector_type(8)))  short bf16x8;
typedef __attribute__((ext_vector_type(4)))  uint  u32x4;

__device__ inline uint rnepk(float a, float b) {
    uint ua = __builtin_bit_cast(uint, a), ub = __builtin_bit_cast(uint, b);
    ua += 0x7FFFu + ((ua >> 16) & 1u);
    ub += 0x7FFFu + ((ub >> 16) & 1u);
    return (ua >> 16) | (ub & 0xFFFF0000u);
}
__device__ inline uint truncpk(float lo, float hi) {   // 1 v_perm_b32
    return __builtin_amdgcn_perm(__builtin_bit_cast(uint, hi),
                                 __builtin_bit_cast(uint, lo), 0x07060302u);
}
__device__ inline f32x16 zero16() {
    f32x16 z;
    #pragma unroll
    for (int i = 0; i < 16; ++i) z[i] = 0.f;
    return z;
}
__device__ inline bf16x8 pack8(f32x4 a, f32x4 c) {
    u32x4 u;
    u.x = rnepk(a[0], a[1]); u.y = rnepk(a[2], a[3]);
    u.z = rnepk(c[0], c[1]); u.w = rnepk(c[2], c[3]);
    return __builtin_bit_cast(bf16x8, u);
}

// (lane,lane^32) quad exchange (validated)
#if __has_builtin(__builtin_amdgcn_permlane32_swap)
__device__ inline void lane32swap(uint& a, uint& b) {
    typedef __attribute__((ext_vector_type(2))) uint u32x2;
    u32x2 r = __builtin_amdgcn_permlane32_swap(a, b, false, false);
    a = r.x; b = r.y;
}
#else
__device__ inline void lane32swap(uint& a, uint& b) {
    const int l5 = (threadIdx.x & 63) >> 5;
    uint send = l5 ? a : b;
    uint recv = __shfl_xor(send, 32);
    uint an = l5 ? recv : a;
    uint bn = l5 ? b : recv;
    a = an; b = bn;
}
#endif

// async global->LDS DMA, 16B/lane: LDS dest = wave-uniform base + lane*16
__device__ inline void dma16(const ushort* g, ushort* l) {
    __builtin_amdgcn_global_load_lds(
        (const __attribute__((address_space(1))) unsigned int*)g,
        (__attribute__((address_space(3))) unsigned int*)l, 16, 0, 0);
}

// softmax quarter for row-group RG of score block SC (order-preserving)
#define SMQ(SC, RG) do {                                                     \
    float p0_ = __builtin_amdgcn_exp2f(SC[RG * 4 + 0]);                      \
    float p1_ = __builtin_amdgcn_exp2f(SC[RG * 4 + 1]);                      \
    float p2_ = __builtin_amdgcn_exp2f(SC[RG * 4 + 2]);                      \
    float p3_ = __builtin_amdgcn_exp2f(SC[RG * 4 + 3]);                      \
    lsum += (p0_ + p1_) + (p2_ + p3_);                                       \
    pr[2 * RG + 0] = truncpk(p0_, p1_);                                      \
    pr[2 * RG + 1] = truncpk(p2_, p3_);                                      \
} while (0)

// quad-exchange pr[] -> two PV A-fragments (identical to validated pp-loop)
#define SWAPPF(PF0, PF1) do {                                                \
    lane32swap(pr[0], pr[2]); lane32swap(pr[1], pr[3]);                      \
    lane32swap(pr[4], pr[6]); lane32swap(pr[5], pr[7]);                      \
    u32x4 u0_; u0_.x = pr[0]; u0_.y = pr[1]; u0_.z = pr[2]; u0_.w = pr[3];   \
    u32x4 u1_; u1_.x = pr[4]; u1_.y = pr[5]; u1_.z = pr[6]; u1_.w = pr[7];   \
    PF0 = __builtin_bit_cast(bf16x8, u0_);                                   \
    PF1 = __builtin_bit_cast(bf16x8, u1_);                                   \
} while (0)

// ---------------------------------------------------------------------------
// Kernel 0: weight prep (unchanged, validated). Wq/Wk/Wv f32 -> frag bf16.
// ---------------------------------------------------------------------------
__global__ __launch_bounds__(256)
void prep_w(const float* __restrict__ Wq, const float* __restrict__ Wk,
            const float* __restrict__ Wv, ushort* __restrict__ Wf)
{
    const int pb = blockIdx.x;                 // 0..23 = proj*8 + h
    const int proj = pb >> 3, h = pb & 7;
    const float* W = (proj == 0 ? Wq : proj == 1 ? Wk : Wv) + h * DH_ * DH_;
    #pragma unroll
    for (int it = 0; it < 2; ++it) {
        const int slot = threadIdx.x + it * 256;   // 512 lane-slots
        const int c = slot >> 6, lane = slot & 63;
        const int l31 = lane & 31, l5 = lane >> 5;
        const int et = c >> 2, st = c & 3;
        const float* wr = W + (et * 32 + l31) * DH_ + st * 16 + l5 * 8;
        bf16x8 v = pack8(*(const f32x4*)wr, *(const f32x4*)(wr + 4));
        *(bf16x8*)(Wf + ((size_t)pb * 8 + c) * 512 + lane * 8) = v;
    }
}

// ---------------------------------------------------------------------------
// Kernel 1: QKV projection (unchanged, validated).
// ---------------------------------------------------------------------------
__global__ __launch_bounds__(256, 2)
void qkv_mfma(const float* __restrict__ x,
              const float* __restrict__ bq, const float* __restrict__ bk,
              const float* __restrict__ bv, const ushort* __restrict__ Wf,
              ushort* __restrict__ Qf, ushort* __restrict__ Kf,
              ushort* __restrict__ Vf)
{
    const int bh = blockIdx.x, b = bh >> 3, h = bh & 7;
    const int sblk = blockIdx.y, s0 = sblk * 128;
    const int tid = threadIdx.x;
    const int w = tid >> 6, lane = tid & 63, l31 = lane & 31, l5 = lane >> 5;

    __shared__ __align__(16) ushort bnc[4][2560];    // per-wave [s][e] stride 72
    __shared__ __align__(16) ushort vsh[64 * 136];   // block-shared Vt [dh][s128]
    ushort* mybnc = bnc[w];

    const ushort* wqb = Wf + ((size_t)(0 * 8 + h)) * 8 * 512;
    const ushort* wkb = Wf + ((size_t)(1 * 8 + h)) * 8 * 512;
    const ushort* wvb = Wf + ((size_t)(2 * 8 + h)) * 8 * 512;

    // ---- x fragments straight from global ----
    const int srow = w * 32 + l31;
    const float* xr = x + ((size_t)(b * S_ + s0 + srow)) * D_ + h * DH_;
    bf16x8 xf[4];
    #pragma unroll
    for (int st = 0; st < 4; ++st)
        xf[st] = pack8(*(const f32x4*)(xr + st * 16 + l5 * 8),
                       *(const f32x4*)(xr + st * 16 + l5 * 8 + 4));

    // ---- K: C[e][s] (A=Wk,B=x) -> bounce [s][e] -> fragment emit ----
    {
        bf16x8 wf[2][4];
        #pragma unroll
        for (int et = 0; et < 2; ++et)
            #pragma unroll
            for (int st = 0; st < 4; ++st)
                wf[et][st] = *(const bf16x8*)(wkb + (et * 4 + st) * 512 + lane * 8);
        #pragma unroll
        for (int et = 0; et < 2; ++et) {
            f32x16 acc = zero16();
            #pragma unroll
            for (int st = 0; st < 4; ++st)
                acc = __builtin_amdgcn_mfma_f32_32x32x16_bf16(wf[et][st], xf[st], acc, 0, 0, 0);
            #pragma unroll
            for (int rg = 0; rg < 4; ++rg) {
                float4 b4 = *(const float4*)(bk + h * DH_ + et * 32 + rg * 8 + l5 * 4);
                uint2 pk;
                pk.x = rnepk(acc[rg * 4 + 0] + b4.x, acc[rg * 4 + 1] + b4.y);
                pk.y = rnepk(acc[rg * 4 + 2] + b4.z, acc[rg * 4 + 3] + b4.w);
                *(uint2*)(mybnc + l31 * 72 + et * 32 + rg * 8 + l5 * 4) = pk;
            }
        }
        const int kt = sblk * 2 + (w >> 1), g = w & 1;
        ushort* kd = Kf + (((size_t)(bh * 32 + kt)) * 2 + g) * 2048;
        #pragma unroll
        for (int st = 0; st < 4; ++st) {
            uint4 v = *(const uint4*)(mybnc + l31 * 72 + st * 16 + l5 * 8);
            *(uint4*)(kd + st * 512 + lane * 8) = v;
        }
    }

    // ---- Q: same, with bias+SCALE, emit tile qt = sblk*4 + w ----
    {
        bf16x8 wf[2][4];
        #pragma unroll
        for (int et = 0; et < 2; ++et)
            #pragma unroll
            for (int st = 0; st < 4; ++st)
                wf[et][st] = *(const bf16x8*)(wqb + (et * 4 + st) * 512 + lane * 8);
        #pragma unroll
        for (int et = 0; et < 2; ++et) {
            f32x16 acc = zero16();
            #pragma unroll
            for (int st = 0; st < 4; ++st)
                acc = __builtin_amdgcn_mfma_f32_32x32x16_bf16(wf[et][st], xf[st], acc, 0, 0, 0);
            #pragma unroll
            for (int rg = 0; rg < 4; ++rg) {
                float4 b4 = *(const float4*)(bq + h * DH_ + et * 32 + rg * 8 + l5 * 4);
                uint2 pk;
                pk.x = rnepk((acc[rg * 4 + 0] + b4.x) * SCALE, (acc[rg * 4 + 1] + b4.y) * SCALE);
                pk.y = rnepk((acc[rg * 4 + 2] + b4.z) * SCALE, (acc[rg * 4 + 3] + b4.w) * SCALE);
                *(uint2*)(mybnc + l31 * 72 + et * 32 + rg * 8 + l5 * 4) = pk;
            }
        }
        ushort* qd = Qf + ((size_t)(bh * 64 + sblk * 4 + w)) * 2048;
        #pragma unroll
        for (int st = 0; st < 4; ++st) {
            uint4 v = *(const uint4*)(mybnc + l31 * 72 + st * 16 + l5 * 8);
            *(uint4*)(qd + st * 512 + lane * 8) = v;
        }
    }

    // ---- V: C[s][e] (A=x,B=Wv) -> block-shared Vt[dh][s128] -> frag emit ----
    {
        bf16x8 wf[2][4];
        #pragma unroll
        for (int et = 0; et < 2; ++et)
            #pragma unroll
            for (int st = 0; st < 4; ++st)
                wf[et][st] = *(const bf16x8*)(wvb + (et * 4 + st) * 512 + lane * 8);
        #pragma unroll
        for (int et = 0; et < 2; ++et) {
            f32x16 acc = zero16();
            #pragma unroll
            for (int st = 0; st < 4; ++st)
                acc = __builtin_amdgcn_mfma_f32_32x32x16_bf16(xf[st], wf[et][st], acc, 0, 0, 0);
            const float bb = bv[h * DH_ + et * 32 + l31];
            #pragma unroll
            for (int rg = 0; rg < 4; ++rg) {
                uint2 pk;
                pk.x = rnepk(acc[rg * 4 + 0] + bb, acc[rg * 4 + 1] + bb);
                pk.y = rnepk(acc[rg * 4 + 2] + bb, acc[rg * 4 + 3] + bb);
                // Vt[dh = et*32+l31][s = w*32 + rg*8 + l5*4 + {0..3}]
                *(uint2*)(vsh + (et * 32 + l31) * 136 + w * 32 + rg * 8 + l5 * 4) = pk;
            }
        }
        __syncthreads();
        #pragma unroll
        for (int i = 0; i < 4; ++i) {
            const int c = w * 4 + i;                 // 16 chunks: [ktl][dht][st]
            const int ktl = c >> 3, dht = (c >> 2) & 1, st = c & 3;
            uint4 v = *(const uint4*)(vsh + (dht * 32 + l31) * 136 + ktl * 64 + st * 16 + l5 * 8);
            *(uint4*)(Vf + (((size_t)(bh * 32 + sblk * 2 + ktl)) * 2 + dht) * 2048
                      + st * 512 + lane * 8) = v;
        }
    }
}

// ---------------------------------------------------------------------------
// Kernel 2: flash, 8-wave blocks (R4 structure: validated DMA/barrier/epilogue)
// with the inner step SOFTWARE-PIPELINED so each wave's emission interleaves
// MFMA and VALU (waves issue in-order; [all-MFMA][all-VALU] phases made the
// pipes run in SUM, not MAX — MfmaUtil stuck at 29% across R1/R3/R4):
//   A: QK chain g0
//   B: QK chain g1 interleaved with softmax(g0) quarters
//   C: PV st0/1 (needs only pf0/pf1) interleaved with softmax(g1)
//   D: PV st2/3
// Pure reordering of independent ops + hoisted zero C-in: bit-identical math
// (sc chains, O0/O1 st-order, lsum g0-then-g1 rg-order all preserved).
// ---------------------------------------------------------------------------
__global__ __launch_bounds__(512, 4)
void flash_mfma(const ushort* __restrict__ Qf, const ushort* __restrict__ Kf,
                const ushort* __restrict__ Vf, float* __restrict__ out)
{
    const int bh = blockIdx.x, qblk = blockIdx.y;
    const int b = bh >> 3, h = bh & 7;
    const int tid = threadIdx.x;
    const int w = tid >> 6, lane = tid & 63, l31 = lane & 31, l5 = lane >> 5;
    const int qi = w & 3, p = w >> 2;    // q-tile within block, K-parity

    // dbuf: buf s at s*16384 ush (32KB): [Kp0 4096][Vp0 4096][Kp1 4096][Vp1 4096]
    // epilogue overlays: 4 x (32q x 68 f32) + 128 lsum = 35328 B
    __shared__ __align__(16) ushort lds_u[32768];    // 65536 B

    // staging role of wave w: region w (4 KB = 4 chunks of 1 KB)
    const ushort* gsrc = (((w >> 1) & 1) ? Vf : Kf)
                         + (size_t)bh * 32 * 4096 + (size_t)(w & 1) * 2048;
    const int stp = w >> 2;              // parity of the tile this wave stages
    ushort* const stdst0 = lds_u + w * 2048;

    // ---- prologue: DMA step-0 tiles (kt = stp) into buf0 ----
    {
        const ushort* gb = gsrc + (size_t)stp * 4096;
        #pragma unroll
        for (int i = 0; i < 4; ++i)
            dma16(gb + i * 512 + lane * 8, stdst0 + i * 512);
    }

    // ---- Q B-frags (coalesced from Qf), tile qblk*4 + qi ----
    bf16x8 qf[4];
    #pragma unroll
    for (int st = 0; st < 4; ++st)
        qf[st] = *(const bf16x8*)(Qf + ((size_t)(bh * 64 + qblk * 4 + qi)) * 2048
                                  + st * 512 + lane * 8);

    const f32x16 fz = zero16();          // shared zero C-in (no per-step movs)
    f32x16 O[2];                         // [dht], O^T cols q = l31
    O[0] = fz; O[1] = fz;
    float lsum = 0.f;

    for (int step = 0; step < 16; ++step) {
        __syncthreads();                 // drains DMAs for buf[cur]
        const ushort* cbuf = lds_u + (step & 1) * 16384;
        if (step < 15) {                 // DMA tile kt=2*(step+1)+stp into other buf
            const ushort* gb = gsrc + (size_t)(2 * (step + 1) + stp) * 4096;
            ushort* ld = lds_u + ((step + 1) & 1) * 16384 + w * 2048;
            #pragma unroll
            for (int i = 0; i < 4; ++i)
                dma16(gb + i * 512 + lane * 8, ld + i * 512);
        }
        const ushort* kreg = cbuf + p * 8192;
        const ushort* vreg = kreg + 4096;

        // ---- A: QK chain g0 ----
        bf16x8 k0 = *(const bf16x8*)(kreg + 0 * 512 + lane * 8);
        bf16x8 k1 = *(const bf16x8*)(kreg + 1 * 512 + lane * 8);
        bf16x8 k2 = *(const bf16x8*)(kreg + 2 * 512 + lane * 8);
        bf16x8 k3 = *(const bf16x8*)(kreg + 3 * 512 + lane * 8);
        __builtin_amdgcn_s_setprio(1);
        f32x16 sc0 = __builtin_amdgcn_mfma_f32_32x32x16_bf16(k0, qf[0], fz,  0, 0, 0);
        sc0        = __builtin_amdgcn_mfma_f32_32x32x16_bf16(k1, qf[1], sc0, 0, 0, 0);
        sc0        = __builtin_amdgcn_mfma_f32_32x32x16_bf16(k2, qf[2], sc0, 0, 0, 0);
        sc0        = __builtin_amdgcn_mfma_f32_32x32x16_bf16(k3, qf[3], sc0, 0, 0, 0);
        __builtin_amdgcn_s_setprio(0);

        // g1 K-frags + V st0/1 frags (independent LDS reads, fill chain gaps)
        bf16x8 g0 = *(const bf16x8*)(kreg + 4 * 512 + lane * 8);
        bf16x8 g1 = *(const bf16x8*)(kreg + 5 * 512 + lane * 8);
        bf16x8 g2 = *(const bf16x8*)(kreg + 6 * 512 + lane * 8);
        bf16x8 g3 = *(const bf16x8*)(kreg + 7 * 512 + lane * 8);
        bf16x8 va0 = *(const bf16x8*)(vreg + 0 * 512 + lane * 8);
        bf16x8 va1 = *(const bf16x8*)(vreg + 1 * 512 + lane * 8);
        bf16x8 vb0 = *(const bf16x8*)(vreg + 4 * 512 + lane * 8);
        bf16x8 vb1 = *(const bf16x8*)(vreg + 5 * 512 + lane * 8);

        // ---- B: QK chain g1 interleaved with softmax(sc0) ----
        uint pr[8];
        f32x16 sc1 = __builtin_amdgcn_mfma_f32_32x32x16_bf16(g0, qf[0], fz,  0, 0, 0);
        SMQ(sc0, 0);
        sc1        = __builtin_amdgcn_mfma_f32_32x32x16_bf16(g1, qf[1], sc1, 0, 0, 0);
        SMQ(sc0, 1);
        sc1        = __builtin_amdgcn_mfma_f32_32x32x16_bf16(g2, qf[2], sc1, 0, 0, 0);
        SMQ(sc0, 2);
        sc1        = __builtin_amdgcn_mfma_f32_32x32x16_bf16(g3, qf[3], sc1, 0, 0, 0);
        SMQ(sc0, 3);
        bf16x8 pf0, pf1;
        SWAPPF(pf0, pf1);

        // ---- C: PV st0/1 interleaved with softmax(sc1) ----
        O[0] = __builtin_amdgcn_mfma_f32_32x32x16_bf16(va0, pf0, O[0], 0, 0, 0);
        SMQ(sc1, 0);
        O[0] = __builtin_amdgcn_mfma_f32_32x32x16_bf16(va1, pf1, O[0], 0, 0, 0);
        SMQ(sc1, 1);
        O[1] = __builtin_amdgcn_mfma_f32_32x32x16_bf16(vb0, pf0, O[1], 0, 0, 0);
        SMQ(sc1, 2);
        O[1] = __builtin_amdgcn_mfma_f32_32x32x16_bf16(vb1, pf1, O[1], 0, 0, 0);
        SMQ(sc1, 3);
        bf16x8 pf2, pf3;
        SWAPPF(pf2, pf3);

        // V st2/3 frags
        bf16x8 va2 = *(const bf16x8*)(vreg + 2 * 512 + lane * 8);
        bf16x8 va3 = *(const bf16x8*)(vreg + 3 * 512 + lane * 8);
        bf16x8 vb2 = *(const bf16x8*)(vreg + 6 * 512 + lane * 8);
        bf16x8 vb3 = *(const bf16x8*)(vreg + 7 * 512 + lane * 8);

        // ---- D: PV st2/3 ----
        __builtin_amdgcn_s_setprio(1);
        O[0] = __builtin_amdgcn_mfma_f32_32x32x16_bf16(va2, pf2, O[0], 0, 0, 0);
        O[0] = __builtin_amdgcn_mfma_f32_32x32x16_bf16(va3, pf3, O[0], 0, 0, 0);
        O[1] = __builtin_amdgcn_mfma_f32_32x32x16_bf16(vb2, pf2, O[1], 0, 0, 0);
        O[1] = __builtin_amdgcn_mfma_f32_32x32x16_bf16(vb3, pf3, O[1], 0, 0, 0);
        __builtin_amdgcn_s_setprio(0);
    }

    // ---- merge parity partners (R1-validated pattern), normalize ----
    lsum += __shfl_xor(lsum, 32);

    __syncthreads();                     // all loop reads done before overlay
    float* mb = (float*)lds_u;           // 4 regions x (32q x 68 f32); lsA after
    float* reg = mb + qi * 2176;
    float* lsA = mb + 4 * 2176;          // 128 slots

    if (p == 1) {                        // odd-parity waves publish partials
        #pragma unroll
        for (int dht = 0; dht < 2; ++dht)
            #pragma unroll
            for (int rg = 0; rg < 4; ++rg) {
                f32x4 v4;
                v4[0] = O[dht][rg * 4 + 0];
                v4[1] = O[dht][rg * 4 + 1];
                v4[2] = O[dht][rg * 4 + 2];
                v4[3] = O[dht][rg * 4 + 3];
                *(f32x4*)(reg + l31 * 68 + dht * 32 + rg * 8 + l5 * 4) = v4;
            }
        if (l5 == 0) lsA[qi * 32 + l31] = lsum;
    }
    __syncthreads();
    if (p == 0) {                        // even-parity waves merge + finalize
        const float linv = 1.0f / (lsum + lsA[qi * 32 + l31]);
        #pragma unroll
        for (int dht = 0; dht < 2; ++dht)
            #pragma unroll
            for (int rg = 0; rg < 4; ++rg) {
                float* a = reg + l31 * 68 + dht * 32 + rg * 8 + l5 * 4;
                f32x4 part = *(const f32x4*)a;
                f32x4 v4;
                v4[0] = (O[dht][rg * 4 + 0] + part[0]) * linv;
                v4[1] = (O[dht][rg * 4 + 1] + part[1]) * linv;
                v4[2] = (O[dht][rg * 4 + 2] + part[2]) * linv;
                v4[3] = (O[dht][rg * 4 + 3] + part[3]) * linv;
                *(f32x4*)a = v4;
            }
    }
    __syncthreads();

    // ---- cooperative coalesced store: 128 rows x 16 chunks of 16B ----
    const int q0 = qblk * 128;
    #pragma unroll
    for (int i = 0; i < 4; ++i) {
        const int slot = tid + 512 * i;
        const int r = slot >> 4, c = slot & 15;
        f32x4 v = *(const f32x4*)(mb + (r >> 5) * 2176 + (r & 31) * 68 + c * 4);
        *(f32x4*)(out + ((size_t)(b * S_ + q0 + r)) * D_ + h * DH_ + c * 4) = v;
    }
}

extern "C" void kernel_launch(void* const* d_in, const int* in_sizes, int n_in,
                              void* d_out, int out_size, void* d_ws, size_t ws_size,
                              hipStream_t stream) {
    const float* x  = (const float*)d_in[0];
    const float* Wq = (const float*)d_in[1];
    const float* bq = (const float*)d_in[2];
    const float* Wk = (const float*)d_in[3];
    const float* bk = (const float*)d_in[4];
    const float* Wv = (const float*)d_in[5];
    const float* bv = (const float*)d_in[6];
    float* outp = (float*)d_out;

    ushort* Qf  = (ushort*)d_ws;                       // frag-linear, 8 MB
    ushort* Kf  = Qf + (size_t)BH_ * S_ * DH_;         // 8 MB
    ushort* Vf  = Kf + (size_t)BH_ * S_ * DH_;         // 8 MB
    ushort* Wfb = Vf + (size_t)BH_ * S_ * DH_;         // 192 KB bf16 W frags

    prep_w<<<dim3(24), 256, 0, stream>>>(Wq, Wk, Wv, Wfb);
    qkv_mfma<<<dim3(BH_, S_ / 128), 256, 0, stream>>>(x, bq, bk, bv, Wfb,
                                                      Qf, Kf, Vf);
    flash_mfma<<<dim3(BH_, 16), 512, 0, stream>>>(Qf, Kf, Vf, outp);
}

// Round 6
// 124.324 us; speedup vs baseline: 1.0137x; 1.0137x over previous
//
#include <hip/hip_runtime.h>
#include <math.h>

#define B_ 4
#define S_ 2048
#define D_ 512
#define H_ 8
#define DH_ 64
#define BH_ (B_*H_)
#define SCALE 0.1803368801111243f   // log2(e)/sqrt(64)

typedef __attribute__((ext_vector_type(4)))  float f32x4;
typedef __attribute__((ext_vector_type(16))) float f32x16;
typedef __attribute__((ext_vector_type(8)))  short bf16x8;
typedef __attribute__((ext_vector_type(4)))  uint  u32x4;

__device__ inline uint rnepk(float a, float b) {
    uint ua = __builtin_bit_cast(uint, a), ub = __builtin_bit_cast(uint, b);
    ua += 0x7FFFu + ((ua >> 16) & 1u);
    ub += 0x7FFFu + ((ub >> 16) & 1u);
    return (ua >> 16) | (ub & 0xFFFF0000u);
}
__device__ inline uint truncpk(float lo, float hi) {   // 1 v_perm_b32
    return __builtin_amdgcn_perm(__builtin_bit_cast(uint, hi),
                                 __builtin_bit_cast(uint, lo), 0x07060302u);
}
__device__ inline f32x16 zero16() {
    f32x16 z;
    #pragma unroll
    for (int i = 0; i < 16; ++i) z[i] = 0.f;
    return z;
}
__device__ inline bf16x8 pack8(f32x4 a, f32x4 c) {
    u32x4 u;
    u.x = rnepk(a[0], a[1]); u.y = rnepk(a[2], a[3]);
    u.z = rnepk(c[0], c[1]); u.w = rnepk(c[2], c[3]);
    return __builtin_bit_cast(bf16x8, u);
}

// (lane,lane^32) quad exchange (validated)
#if __has_builtin(__builtin_amdgcn_permlane32_swap)
__device__ inline void lane32swap(uint& a, uint& b) {
    typedef __attribute__((ext_vector_type(2))) uint u32x2;
    u32x2 r = __builtin_amdgcn_permlane32_swap(a, b, false, false);
    a = r.x; b = r.y;
}
#else
__device__ inline void lane32swap(uint& a, uint& b) {
    const int l5 = (threadIdx.x & 63) >> 5;
    uint send = l5 ? a : b;
    uint recv = __shfl_xor(send, 32);
    uint an = l5 ? recv : a;
    uint bn = l5 ? b : recv;
    a = an; b = bn;
}
#endif

// async global->LDS DMA, 16B/lane: LDS dest = wave-uniform base + lane*16
__device__ inline void dma16(const ushort* g, ushort* l) {
    __builtin_amdgcn_global_load_lds(
        (const __attribute__((address_space(1))) unsigned int*)g,
        (__attribute__((address_space(3))) unsigned int*)l, 16, 0, 0);
}

// softmax quarter for row-group RG of score block SC (order-preserving)
#define SMQ(SC, RG) do {                                                     \
    float p0_ = __builtin_amdgcn_exp2f(SC[RG * 4 + 0]);                      \
    float p1_ = __builtin_amdgcn_exp2f(SC[RG * 4 + 1]);                      \
    float p2_ = __builtin_amdgcn_exp2f(SC[RG * 4 + 2]);                      \
    float p3_ = __builtin_amdgcn_exp2f(SC[RG * 4 + 3]);                      \
    lsum += (p0_ + p1_) + (p2_ + p3_);                                       \
    pr[2 * RG + 0] = truncpk(p0_, p1_);                                      \
    pr[2 * RG + 1] = truncpk(p2_, p3_);                                      \
} while (0)

// quad-exchange pr[] -> two PV A-fragments (identical to validated pp-loop)
#define SWAPPF(PF0, PF1) do {                                                \
    lane32swap(pr[0], pr[2]); lane32swap(pr[1], pr[3]);                      \
    lane32swap(pr[4], pr[6]); lane32swap(pr[5], pr[7]);                      \
    u32x4 u0_; u0_.x = pr[0]; u0_.y = pr[1]; u0_.z = pr[2]; u0_.w = pr[3];   \
    u32x4 u1_; u1_.x = pr[4]; u1_.y = pr[5]; u1_.z = pr[6]; u1_.w = pr[7];   \
    PF0 = __builtin_bit_cast(bf16x8, u0_);                                   \
    PF1 = __builtin_bit_cast(bf16x8, u1_);                                   \
} while (0)

// ---------------------------------------------------------------------------
// Kernel 0: weight prep (unchanged, validated). Wq/Wk/Wv f32 -> frag bf16.
// ---------------------------------------------------------------------------
__global__ __launch_bounds__(256)
void prep_w(const float* __restrict__ Wq, const float* __restrict__ Wk,
            const float* __restrict__ Wv, ushort* __restrict__ Wf)
{
    const int pb = blockIdx.x;                 // 0..23 = proj*8 + h
    const int proj = pb >> 3, h = pb & 7;
    const float* W = (proj == 0 ? Wq : proj == 1 ? Wk : Wv) + h * DH_ * DH_;
    #pragma unroll
    for (int it = 0; it < 2; ++it) {
        const int slot = threadIdx.x + it * 256;   // 512 lane-slots
        const int c = slot >> 6, lane = slot & 63;
        const int l31 = lane & 31, l5 = lane >> 5;
        const int et = c >> 2, st = c & 3;
        const float* wr = W + (et * 32 + l31) * DH_ + st * 16 + l5 * 8;
        bf16x8 v = pack8(*(const f32x4*)wr, *(const f32x4*)(wr + 4));
        *(bf16x8*)(Wf + ((size_t)pb * 8 + c) * 512 + lane * 8) = v;
    }
}

// ---------------------------------------------------------------------------
// Kernel 1: QKV projection. CHANGE vs R5: the x fragments are no longer
// gathered straight from global (lane l31 selects the row -> 32 cache lines
// per f32x4 load, latency-bound at 2 blocks/CU). The block's x-slice
// (128 rows x 64 f32) is first staged into LDS with fully coalesced loads
// (16 lanes x 16B per row, every 64B line fully consumed), then fragments
// are built from LDS (stride 68 f32: 16B-aligned rows, 4-way bank alias).
// f32 values reaching pack8 are bit-identical -> outputs bit-identical.
// Everything else (W frags, MFMA, bounce, emit layouts) unchanged/validated.
// ---------------------------------------------------------------------------
__global__ __launch_bounds__(256, 2)
void qkv_mfma(const float* __restrict__ x,
              const float* __restrict__ bq, const float* __restrict__ bk,
              const float* __restrict__ bv, const ushort* __restrict__ Wf,
              ushort* __restrict__ Qf, ushort* __restrict__ Kf,
              ushort* __restrict__ Vf)
{
    const int bh = blockIdx.x, b = bh >> 3, h = bh & 7;
    const int sblk = blockIdx.y, s0 = sblk * 128;
    const int tid = threadIdx.x;
    const int w = tid >> 6, lane = tid & 63, l31 = lane & 31, l5 = lane >> 5;

    __shared__ __align__(16) ushort bnc[4][2560];    // per-wave [s][e] stride 72
    __shared__ __align__(16) ushort vsh[64 * 136];   // block-shared Vt [dh][s128]
    __shared__ __align__(16) float  xs[128 * 68];    // staged x-slice (34 KB)
    ushort* mybnc = bnc[w];

    const ushort* wqb = Wf + ((size_t)(0 * 8 + h)) * 8 * 512;
    const ushort* wkb = Wf + ((size_t)(1 * 8 + h)) * 8 * 512;
    const ushort* wvb = Wf + ((size_t)(2 * 8 + h)) * 8 * 512;

    // ---- coalesced x stage: 8 passes x (16 rows x 16 lanes x 16B) ----
    #pragma unroll
    for (int ps = 0; ps < 8; ++ps) {
        const int r = ps * 16 + (tid >> 4), c16 = tid & 15;
        f32x4 v = *(const f32x4*)(x + ((size_t)(b * S_ + s0 + r)) * D_
                                  + h * DH_ + c16 * 4);
        *(f32x4*)(xs + r * 68 + c16 * 4) = v;
    }
    __syncthreads();

    // ---- x fragments from LDS ----
    const int srow = w * 32 + l31;
    bf16x8 xf[4];
    #pragma unroll
    for (int st = 0; st < 4; ++st)
        xf[st] = pack8(*(const f32x4*)(xs + srow * 68 + st * 16 + l5 * 8),
                       *(const f32x4*)(xs + srow * 68 + st * 16 + l5 * 8 + 4));

    // ---- K: C[e][s] (A=Wk,B=x) -> bounce [s][e] -> fragment emit ----
    {
        bf16x8 wf[2][4];
        #pragma unroll
        for (int et = 0; et < 2; ++et)
            #pragma unroll
            for (int st = 0; st < 4; ++st)
                wf[et][st] = *(const bf16x8*)(wkb + (et * 4 + st) * 512 + lane * 8);
        #pragma unroll
        for (int et = 0; et < 2; ++et) {
            f32x16 acc = zero16();
            #pragma unroll
            for (int st = 0; st < 4; ++st)
                acc = __builtin_amdgcn_mfma_f32_32x32x16_bf16(wf[et][st], xf[st], acc, 0, 0, 0);
            #pragma unroll
            for (int rg = 0; rg < 4; ++rg) {
                float4 b4 = *(const float4*)(bk + h * DH_ + et * 32 + rg * 8 + l5 * 4);
                uint2 pk;
                pk.x = rnepk(acc[rg * 4 + 0] + b4.x, acc[rg * 4 + 1] + b4.y);
                pk.y = rnepk(acc[rg * 4 + 2] + b4.z, acc[rg * 4 + 3] + b4.w);
                *(uint2*)(mybnc + l31 * 72 + et * 32 + rg * 8 + l5 * 4) = pk;
            }
        }
        const int kt = sblk * 2 + (w >> 1), g = w & 1;
        ushort* kd = Kf + (((size_t)(bh * 32 + kt)) * 2 + g) * 2048;
        #pragma unroll
        for (int st = 0; st < 4; ++st) {
            uint4 v = *(const uint4*)(mybnc + l31 * 72 + st * 16 + l5 * 8);
            *(uint4*)(kd + st * 512 + lane * 8) = v;
        }
    }

    // ---- Q: same, with bias+SCALE, emit tile qt = sblk*4 + w ----
    {
        bf16x8 wf[2][4];
        #pragma unroll
        for (int et = 0; et < 2; ++et)
            #pragma unroll
            for (int st = 0; st < 4; ++st)
                wf[et][st] = *(const bf16x8*)(wqb + (et * 4 + st) * 512 + lane * 8);
        #pragma unroll
        for (int et = 0; et < 2; ++et) {
            f32x16 acc = zero16();
            #pragma unroll
            for (int st = 0; st < 4; ++st)
                acc = __builtin_amdgcn_mfma_f32_32x32x16_bf16(wf[et][st], xf[st], acc, 0, 0, 0);
            #pragma unroll
            for (int rg = 0; rg < 4; ++rg) {
                float4 b4 = *(const float4*)(bq + h * DH_ + et * 32 + rg * 8 + l5 * 4);
                uint2 pk;
                pk.x = rnepk((acc[rg * 4 + 0] + b4.x) * SCALE, (acc[rg * 4 + 1] + b4.y) * SCALE);
                pk.y = rnepk((acc[rg * 4 + 2] + b4.z) * SCALE, (acc[rg * 4 + 3] + b4.w) * SCALE);
                *(uint2*)(mybnc + l31 * 72 + et * 32 + rg * 8 + l5 * 4) = pk;
            }
        }
        ushort* qd = Qf + ((size_t)(bh * 64 + sblk * 4 + w)) * 2048;
        #pragma unroll
        for (int st = 0; st < 4; ++st) {
            uint4 v = *(const uint4*)(mybnc + l31 * 72 + st * 16 + l5 * 8);
            *(uint4*)(qd + st * 512 + lane * 8) = v;
        }
    }

    // ---- V: C[s][e] (A=x,B=Wv) -> block-shared Vt[dh][s128] -> frag emit ----
    {
        bf16x8 wf[2][4];
        #pragma unroll
        for (int et = 0; et < 2; ++et)
            #pragma unroll
            for (int st = 0; st < 4; ++st)
                wf[et][st] = *(const bf16x8*)(wvb + (et * 4 + st) * 512 + lane * 8);
        #pragma unroll
        for (int et = 0; et < 2; ++et) {
            f32x16 acc = zero16();
            #pragma unroll
            for (int st = 0; st < 4; ++st)
                acc = __builtin_amdgcn_mfma_f32_32x32x16_bf16(xf[st], wf[et][st], acc, 0, 0, 0);
            const float bb = bv[h * DH_ + et * 32 + l31];
            #pragma unroll
            for (int rg = 0; rg < 4; ++rg) {
                uint2 pk;
                pk.x = rnepk(acc[rg * 4 + 0] + bb, acc[rg * 4 + 1] + bb);
                pk.y = rnepk(acc[rg * 4 + 2] + bb, acc[rg * 4 + 3] + bb);
                // Vt[dh = et*32+l31][s = w*32 + rg*8 + l5*4 + {0..3}]
                *(uint2*)(vsh + (et * 32 + l31) * 136 + w * 32 + rg * 8 + l5 * 4) = pk;
            }
        }
        __syncthreads();
        #pragma unroll
        for (int i = 0; i < 4; ++i) {
            const int c = w * 4 + i;                 // 16 chunks: [ktl][dht][st]
            const int ktl = c >> 3, dht = (c >> 2) & 1, st = c & 3;
            uint4 v = *(const uint4*)(vsh + (dht * 32 + l31) * 136 + ktl * 64 + st * 16 + l5 * 8);
            *(uint4*)(Vf + (((size_t)(bh * 32 + sblk * 2 + ktl)) * 2 + dht) * 2048
                      + st * 512 + lane * 8) = v;
        }
    }
}

// ---------------------------------------------------------------------------
// Kernel 2: flash (unchanged from R5/R4, validated at 45.6 us).
// ---------------------------------------------------------------------------
__global__ __launch_bounds__(512, 4)
void flash_mfma(const ushort* __restrict__ Qf, const ushort* __restrict__ Kf,
                const ushort* __restrict__ Vf, float* __restrict__ out)
{
    const int bh = blockIdx.x, qblk = blockIdx.y;
    const int b = bh >> 3, h = bh & 7;
    const int tid = threadIdx.x;
    const int w = tid >> 6, lane = tid & 63, l31 = lane & 31, l5 = lane >> 5;
    const int qi = w & 3, p = w >> 2;    // q-tile within block, K-parity

    // dbuf: buf s at s*16384 ush (32KB): [Kp0 4096][Vp0 4096][Kp1 4096][Vp1 4096]
    // epilogue overlays: 4 x (32q x 68 f32) + 128 lsum = 35328 B
    __shared__ __align__(16) ushort lds_u[32768];    // 65536 B

    // staging role of wave w: region w (4 KB = 4 chunks of 1 KB)
    const ushort* gsrc = (((w >> 1) & 1) ? Vf : Kf)
                         + (size_t)bh * 32 * 4096 + (size_t)(w & 1) * 2048;
    const int stp = w >> 2;              // parity of the tile this wave stages
    ushort* const stdst0 = lds_u + w * 2048;

    // ---- prologue: DMA step-0 tiles (kt = stp) into buf0 ----
    {
        const ushort* gb = gsrc + (size_t)stp * 4096;
        #pragma unroll
        for (int i = 0; i < 4; ++i)
            dma16(gb + i * 512 + lane * 8, stdst0 + i * 512);
    }

    // ---- Q B-frags (coalesced from Qf), tile qblk*4 + qi ----
    bf16x8 qf[4];
    #pragma unroll
    for (int st = 0; st < 4; ++st)
        qf[st] = *(const bf16x8*)(Qf + ((size_t)(bh * 64 + qblk * 4 + qi)) * 2048
                                  + st * 512 + lane * 8);

    const f32x16 fz = zero16();          // shared zero C-in (no per-step movs)
    f32x16 O[2];                         // [dht], O^T cols q = l31
    O[0] = fz; O[1] = fz;
    float lsum = 0.f;

    for (int step = 0; step < 16; ++step) {
        __syncthreads();                 // drains DMAs for buf[cur]
        const ushort* cbuf = lds_u + (step & 1) * 16384;
        if (step < 15) {                 // DMA tile kt=2*(step+1)+stp into other buf
            const ushort* gb = gsrc + (size_t)(2 * (step + 1) + stp) * 4096;
            ushort* ld = lds_u + ((step + 1) & 1) * 16384 + w * 2048;
            #pragma unroll
            for (int i = 0; i < 4; ++i)
                dma16(gb + i * 512 + lane * 8, ld + i * 512);
        }
        const ushort* kreg = cbuf + p * 8192;
        const ushort* vreg = kreg + 4096;

        // ---- A: QK chain g0 ----
        bf16x8 k0 = *(const bf16x8*)(kreg + 0 * 512 + lane * 8);
        bf16x8 k1 = *(const bf16x8*)(kreg + 1 * 512 + lane * 8);
        bf16x8 k2 = *(const bf16x8*)(kreg + 2 * 512 + lane * 8);
        bf16x8 k3 = *(const bf16x8*)(kreg + 3 * 512 + lane * 8);
        __builtin_amdgcn_s_setprio(1);
        f32x16 sc0 = __builtin_amdgcn_mfma_f32_32x32x16_bf16(k0, qf[0], fz,  0, 0, 0);
        sc0        = __builtin_amdgcn_mfma_f32_32x32x16_bf16(k1, qf[1], sc0, 0, 0, 0);
        sc0        = __builtin_amdgcn_mfma_f32_32x32x16_bf16(k2, qf[2], sc0, 0, 0, 0);
        sc0        = __builtin_amdgcn_mfma_f32_32x32x16_bf16(k3, qf[3], sc0, 0, 0, 0);
        __builtin_amdgcn_s_setprio(0);

        // g1 K-frags + V st0/1 frags (independent LDS reads, fill chain gaps)
        bf16x8 g0 = *(const bf16x8*)(kreg + 4 * 512 + lane * 8);
        bf16x8 g1 = *(const bf16x8*)(kreg + 5 * 512 + lane * 8);
        bf16x8 g2 = *(const bf16x8*)(kreg + 6 * 512 + lane * 8);
        bf16x8 g3 = *(const bf16x8*)(kreg + 7 * 512 + lane * 8);
        bf16x8 va0 = *(const bf16x8*)(vreg + 0 * 512 + lane * 8);
        bf16x8 va1 = *(const bf16x8*)(vreg + 1 * 512 + lane * 8);
        bf16x8 vb0 = *(const bf16x8*)(vreg + 4 * 512 + lane * 8);
        bf16x8 vb1 = *(const bf16x8*)(vreg + 5 * 512 + lane * 8);

        // ---- B: QK chain g1 interleaved with softmax(sc0) ----
        uint pr[8];
        f32x16 sc1 = __builtin_amdgcn_mfma_f32_32x32x16_bf16(g0, qf[0], fz,  0, 0, 0);
        SMQ(sc0, 0);
        sc1        = __builtin_amdgcn_mfma_f32_32x32x16_bf16(g1, qf[1], sc1, 0, 0, 0);
        SMQ(sc0, 1);
        sc1        = __builtin_amdgcn_mfma_f32_32x32x16_bf16(g2, qf[2], sc1, 0, 0, 0);
        SMQ(sc0, 2);
        sc1        = __builtin_amdgcn_mfma_f32_32x32x16_bf16(g3, qf[3], sc1, 0, 0, 0);
        SMQ(sc0, 3);
        bf16x8 pf0, pf1;
        SWAPPF(pf0, pf1);

        // ---- C: PV st0/1 interleaved with softmax(sc1) ----
        O[0] = __builtin_amdgcn_mfma_f32_32x32x16_bf16(va0, pf0, O[0], 0, 0, 0);
        SMQ(sc1, 0);
        O[0] = __builtin_amdgcn_mfma_f32_32x32x16_bf16(va1, pf1, O[0], 0, 0, 0);
        SMQ(sc1, 1);
        O[1] = __builtin_amdgcn_mfma_f32_32x32x16_bf16(vb0, pf0, O[1], 0, 0, 0);
        SMQ(sc1, 2);
        O[1] = __builtin_amdgcn_mfma_f32_32x32x16_bf16(vb1, pf1, O[1], 0, 0, 0);
        SMQ(sc1, 3);
        bf16x8 pf2, pf3;
        SWAPPF(pf2, pf3);

        // V st2/3 frags
        bf16x8 va2 = *(const bf16x8*)(vreg + 2 * 512 + lane * 8);
        bf16x8 va3 = *(const bf16x8*)(vreg + 3 * 512 + lane * 8);
        bf16x8 vb2 = *(const bf16x8*)(vreg + 6 * 512 + lane * 8);
        bf16x8 vb3 = *(const bf16x8*)(vreg + 7 * 512 + lane * 8);

        // ---- D: PV st2/3 ----
        __builtin_amdgcn_s_setprio(1);
        O[0] = __builtin_amdgcn_mfma_f32_32x32x16_bf16(va2, pf2, O[0], 0, 0, 0);
        O[0] = __builtin_amdgcn_mfma_f32_32x32x16_bf16(va3, pf3, O[0], 0, 0, 0);
        O[1] = __builtin_amdgcn_mfma_f32_32x32x16_bf16(vb2, pf2, O[1], 0, 0, 0);
        O[1] = __builtin_amdgcn_mfma_f32_32x32x16_bf16(vb3, pf3, O[1], 0, 0, 0);
        __builtin_amdgcn_s_setprio(0);
    }

    // ---- merge parity partners (R1-validated pattern), normalize ----
    lsum += __shfl_xor(lsum, 32);

    __syncthreads();                     // all loop reads done before overlay
    float* mb = (float*)lds_u;           // 4 regions x (32q x 68 f32); lsA after
    float* reg = mb + qi * 2176;
    float* lsA = mb + 4 * 2176;          // 128 slots

    if (p == 1) {                        // odd-parity waves publish partials
        #pragma unroll
        for (int dht = 0; dht < 2; ++dht)
            #pragma unroll
            for (int rg = 0; rg < 4; ++rg) {
                f32x4 v4;
                v4[0] = O[dht][rg * 4 + 0];
                v4[1] = O[dht][rg * 4 + 1];
                v4[2] = O[dht][rg * 4 + 2];
                v4[3] = O[dht][rg * 4 + 3];
                *(f32x4*)(reg + l31 * 68 + dht * 32 + rg * 8 + l5 * 4) = v4;
            }
        if (l5 == 0) lsA[qi * 32 + l31] = lsum;
    }
    __syncthreads();
    if (p == 0) {                        // even-parity waves merge + finalize
        const float linv = 1.0f / (lsum + lsA[qi * 32 + l31]);
        #pragma unroll
        for (int dht = 0; dht < 2; ++dht)
            #pragma unroll
            for (int rg = 0; rg < 4; ++rg) {
                float* a = reg + l31 * 68 + dht * 32 + rg * 8 + l5 * 4;
                f32x4 part = *(const f32x4*)a;
                f32x4 v4;
                v4[0] = (O[dht][rg * 4 + 0] + part[0]) * linv;
                v4[1] = (O[dht][rg * 4 + 1] + part[1]) * linv;
                v4[2] = (O[dht][rg * 4 + 2] + part[2]) * linv;
                v4[3] = (O[dht][rg * 4 + 3] + part[3]) * linv;
                *(f32x4*)a = v4;
            }
    }
    __syncthreads();

    // ---- cooperative coalesced store: 128 rows x 16 chunks of 16B ----
    const int q0 = qblk * 128;
    #pragma unroll
    for (int i = 0; i < 4; ++i) {
        const int slot = tid + 512 * i;
        const int r = slot >> 4, c = slot & 15;
        f32x4 v = *(const f32x4*)(mb + (r >> 5) * 2176 + (r & 31) * 68 + c * 4);
        *(f32x4*)(out + ((size_t)(b * S_ + q0 + r)) * D_ + h * DH_ + c * 4) = v;
    }
}

extern "C" void kernel_launch(void* const* d_in, const int* in_sizes, int n_in,
                              void* d_out, int out_size, void* d_ws, size_t ws_size,
                              hipStream_t stream) {
    const float* x  = (const float*)d_in[0];
    const float* Wq = (const float*)d_in[1];
    const float* bq = (const float*)d_in[2];
    const float* Wk = (const float*)d_in[3];
    const float* bk = (const float*)d_in[4];
    const float* Wv = (const float*)d_in[5];
    const float* bv = (const float*)d_in[6];
    float* outp = (float*)d_out;

    ushort* Qf  = (ushort*)d_ws;                       // frag-linear, 8 MB
    ushort* Kf  = Qf + (size_t)BH_ * S_ * DH_;         // 8 MB
    ushort* Vf  = Kf + (size_t)BH_ * S_ * DH_;         // 8 MB
    ushort* Wfb = Vf + (size_t)BH_ * S_ * DH_;         // 192 KB bf16 W frags

    prep_w<<<dim3(24), 256, 0, stream>>>(Wq, Wk, Wv, Wfb);
    qkv_mfma<<<dim3(BH_, S_ / 128), 256, 0, stream>>>(x, bq, bk, bv, Wfb,
                                                      Qf, Kf, Vf);
    flash_mfma<<<dim3(BH_, 16), 512, 0, stream>>>(Qf, Kf, Vf, outp);
}

// Round 7
// 124.253 us; speedup vs baseline: 1.0143x; 1.0006x over previous
//
#include <hip/hip_runtime.h>
#include <math.h>

#define B_ 4
#define S_ 2048
#define D_ 512
#define H_ 8
#define DH_ 64
#define BH_ (B_*H_)
#define SCALE 0.1803368801111243f   // log2(e)/sqrt(64)

typedef __attribute__((ext_vector_type(4)))  float f32x4;
typedef __attribute__((ext_vector_type(16))) float f32x16;
typedef __attribute__((ext_vector_type(8)))  short bf16x8;
typedef __attribute__((ext_vector_type(4)))  uint  u32x4;

__device__ inline uint rnepk(float a, float b) {
    uint ua = __builtin_bit_cast(uint, a), ub = __builtin_bit_cast(uint, b);
    ua += 0x7FFFu + ((ua >> 16) & 1u);
    ub += 0x7FFFu + ((ub >> 16) & 1u);
    return (ua >> 16) | (ub & 0xFFFF0000u);
}
__device__ inline uint truncpk(float lo, float hi) {   // 1 v_perm_b32
    return __builtin_amdgcn_perm(__builtin_bit_cast(uint, hi),
                                 __builtin_bit_cast(uint, lo), 0x07060302u);
}
__device__ inline f32x16 zero16() {
    f32x16 z;
    #pragma unroll
    for (int i = 0; i < 16; ++i) z[i] = 0.f;
    return z;
}
__device__ inline bf16x8 pack8(f32x4 a, f32x4 c) {
    u32x4 u;
    u.x = rnepk(a[0], a[1]); u.y = rnepk(a[2], a[3]);
    u.z = rnepk(c[0], c[1]); u.w = rnepk(c[2], c[3]);
    return __builtin_bit_cast(bf16x8, u);
}

// (lane,lane^32) quad exchange (validated)
#if __has_builtin(__builtin_amdgcn_permlane32_swap)
__device__ inline void lane32swap(uint& a, uint& b) {
    typedef __attribute__((ext_vector_type(2))) uint u32x2;
    u32x2 r = __builtin_amdgcn_permlane32_swap(a, b, false, false);
    a = r.x; b = r.y;
}
#else
__device__ inline void lane32swap(uint& a, uint& b) {
    const int l5 = (threadIdx.x & 63) >> 5;
    uint send = l5 ? a : b;
    uint recv = __shfl_xor(send, 32);
    uint an = l5 ? recv : a;
    uint bn = l5 ? b : recv;
    a = an; b = bn;
}
#endif

// async global->LDS DMA, 16B/lane: LDS dest = wave-uniform base + lane*16
__device__ inline void dma16(const ushort* g, ushort* l) {
    __builtin_amdgcn_global_load_lds(
        (const __attribute__((address_space(1))) unsigned int*)g,
        (__attribute__((address_space(3))) unsigned int*)l, 16, 0, 0);
}

// softmax quarter for row-group RG of score block SC (order-preserving)
#define SMQ(SC, RG) do {                                                     \
    float p0_ = __builtin_amdgcn_exp2f(SC[RG * 4 + 0]);                      \
    float p1_ = __builtin_amdgcn_exp2f(SC[RG * 4 + 1]);                      \
    float p2_ = __builtin_amdgcn_exp2f(SC[RG * 4 + 2]);                      \
    float p3_ = __builtin_amdgcn_exp2f(SC[RG * 4 + 3]);                      \
    lsum += (p0_ + p1_) + (p2_ + p3_);                                       \
    pr[2 * RG + 0] = truncpk(p0_, p1_);                                      \
    pr[2 * RG + 1] = truncpk(p2_, p3_);                                      \
} while (0)

// quad-exchange pr[] -> two PV A-fragments (identical to validated pp-loop)
#define SWAPPF(PF0, PF1) do {                                                \
    lane32swap(pr[0], pr[2]); lane32swap(pr[1], pr[3]);                      \
    lane32swap(pr[4], pr[6]); lane32swap(pr[5], pr[7]);                      \
    u32x4 u0_; u0_.x = pr[0]; u0_.y = pr[1]; u0_.z = pr[2]; u0_.w = pr[3];   \
    u32x4 u1_; u1_.x = pr[4]; u1_.y = pr[5]; u1_.z = pr[6]; u1_.w = pr[7];   \
    PF0 = __builtin_bit_cast(bf16x8, u0_);                                   \
    PF1 = __builtin_bit_cast(bf16x8, u1_);                                   \
} while (0)

// ---------------------------------------------------------------------------
// Kernel 0: weight prep (unchanged, validated). Wq/Wk/Wv f32 -> frag bf16.
// ---------------------------------------------------------------------------
__global__ __launch_bounds__(256)
void prep_w(const float* __restrict__ Wq, const float* __restrict__ Wk,
            const float* __restrict__ Wv, ushort* __restrict__ Wf)
{
    const int pb = blockIdx.x;                 // 0..23 = proj*8 + h
    const int proj = pb >> 3, h = pb & 7;
    const float* W = (proj == 0 ? Wq : proj == 1 ? Wk : Wv) + h * DH_ * DH_;
    #pragma unroll
    for (int it = 0; it < 2; ++it) {
        const int slot = threadIdx.x + it * 256;   // 512 lane-slots
        const int c = slot >> 6, lane = slot & 63;
        const int l31 = lane & 31, l5 = lane >> 5;
        const int et = c >> 2, st = c & 3;
        const float* wr = W + (et * 32 + l31) * DH_ + st * 16 + l5 * 8;
        bf16x8 v = pack8(*(const f32x4*)wr, *(const f32x4*)(wr + 4));
        *(bf16x8*)(Wf + ((size_t)pb * 8 + c) * 512 + lane * 8) = v;
    }
}

// ---------------------------------------------------------------------------
// Kernel 1: QKV projection. CHANGE vs R6: LDS union. The xs staging buffer
// (34.8 KB) is DEAD once the x-fragments are in registers, and bnc/vsh are
// first written after that point — so xs now aliases bnc+vsh (37.9 KB total
// vs 72.7 KB before), with one added __syncthreads() separating the last xs
// read from the first bnc write. LDS 72.7->37.9 KB lifts occupancy from
// 2 to 4 blocks/CU (4 waves/SIMD) for the latency-bound per-wave chain.
// All arithmetic and emit layouts identical -> bit-identical output.
// ---------------------------------------------------------------------------
__global__ __launch_bounds__(256, 4)
void qkv_mfma(const float* __restrict__ x,
              const float* __restrict__ bq, const float* __restrict__ bk,
              const float* __restrict__ bv, const ushort* __restrict__ Wf,
              ushort* __restrict__ Qf, ushort* __restrict__ Kf,
              ushort* __restrict__ Vf)
{
    const int bh = blockIdx.x, b = bh >> 3, h = bh & 7;
    const int sblk = blockIdx.y, s0 = sblk * 128;
    const int tid = threadIdx.x;
    const int w = tid >> 6, lane = tid & 63, l31 = lane & 31, l5 = lane >> 5;

    // union: [bnc 4x2560 ush = 20480 B][vsh 64x136 ush = 17408 B] = 37888 B
    //        overlaid by xs (128x68 f32 = 34816 B), dead after xf build
    __shared__ __align__(16) ushort smem_u[18944];
    ushort* mybnc = smem_u + w * 2560;               // per-wave bounce
    ushort* vsh   = smem_u + 10240;                  // block-shared Vt
    float*  xs    = (float*)smem_u;                  // staged x (aliases above)

    const ushort* wqb = Wf + ((size_t)(0 * 8 + h)) * 8 * 512;
    const ushort* wkb = Wf + ((size_t)(1 * 8 + h)) * 8 * 512;
    const ushort* wvb = Wf + ((size_t)(2 * 8 + h)) * 8 * 512;

    // ---- coalesced x stage: 8 passes x (16 rows x 16 lanes x 16B) ----
    #pragma unroll
    for (int ps = 0; ps < 8; ++ps) {
        const int r = ps * 16 + (tid >> 4), c16 = tid & 15;
        f32x4 v = *(const f32x4*)(x + ((size_t)(b * S_ + s0 + r)) * D_
                                  + h * DH_ + c16 * 4);
        *(f32x4*)(xs + r * 68 + c16 * 4) = v;
    }
    __syncthreads();

    // ---- x fragments from LDS ----
    const int srow = w * 32 + l31;
    bf16x8 xf[4];
    #pragma unroll
    for (int st = 0; st < 4; ++st)
        xf[st] = pack8(*(const f32x4*)(xs + srow * 68 + st * 16 + l5 * 8),
                       *(const f32x4*)(xs + srow * 68 + st * 16 + l5 * 8 + 4));
    __syncthreads();                     // xs dead; bnc/vsh may now overwrite

    // ---- K: C[e][s] (A=Wk,B=x) -> bounce [s][e] -> fragment emit ----
    {
        bf16x8 wf[2][4];
        #pragma unroll
        for (int et = 0; et < 2; ++et)
            #pragma unroll
            for (int st = 0; st < 4; ++st)
                wf[et][st] = *(const bf16x8*)(wkb + (et * 4 + st) * 512 + lane * 8);
        #pragma unroll
        for (int et = 0; et < 2; ++et) {
            f32x16 acc = zero16();
            #pragma unroll
            for (int st = 0; st < 4; ++st)
                acc = __builtin_amdgcn_mfma_f32_32x32x16_bf16(wf[et][st], xf[st], acc, 0, 0, 0);
            #pragma unroll
            for (int rg = 0; rg < 4; ++rg) {
                float4 b4 = *(const float4*)(bk + h * DH_ + et * 32 + rg * 8 + l5 * 4);
                uint2 pk;
                pk.x = rnepk(acc[rg * 4 + 0] + b4.x, acc[rg * 4 + 1] + b4.y);
                pk.y = rnepk(acc[rg * 4 + 2] + b4.z, acc[rg * 4 + 3] + b4.w);
                *(uint2*)(mybnc + l31 * 72 + et * 32 + rg * 8 + l5 * 4) = pk;
            }
        }
        const int kt = sblk * 2 + (w >> 1), g = w & 1;
        ushort* kd = Kf + (((size_t)(bh * 32 + kt)) * 2 + g) * 2048;
        #pragma unroll
        for (int st = 0; st < 4; ++st) {
            uint4 v = *(const uint4*)(mybnc + l31 * 72 + st * 16 + l5 * 8);
            *(uint4*)(kd + st * 512 + lane * 8) = v;
        }
    }

    // ---- Q: same, with bias+SCALE, emit tile qt = sblk*4 + w ----
    {
        bf16x8 wf[2][4];
        #pragma unroll
        for (int et = 0; et < 2; ++et)
            #pragma unroll
            for (int st = 0; st < 4; ++st)
                wf[et][st] = *(const bf16x8*)(wqb + (et * 4 + st) * 512 + lane * 8);
        #pragma unroll
        for (int et = 0; et < 2; ++et) {
            f32x16 acc = zero16();
            #pragma unroll
            for (int st = 0; st < 4; ++st)
                acc = __builtin_amdgcn_mfma_f32_32x32x16_bf16(wf[et][st], xf[st], acc, 0, 0, 0);
            #pragma unroll
            for (int rg = 0; rg < 4; ++rg) {
                float4 b4 = *(const float4*)(bq + h * DH_ + et * 32 + rg * 8 + l5 * 4);
                uint2 pk;
                pk.x = rnepk((acc[rg * 4 + 0] + b4.x) * SCALE, (acc[rg * 4 + 1] + b4.y) * SCALE);
                pk.y = rnepk((acc[rg * 4 + 2] + b4.z) * SCALE, (acc[rg * 4 + 3] + b4.w) * SCALE);
                *(uint2*)(mybnc + l31 * 72 + et * 32 + rg * 8 + l5 * 4) = pk;
            }
        }
        ushort* qd = Qf + ((size_t)(bh * 64 + sblk * 4 + w)) * 2048;
        #pragma unroll
        for (int st = 0; st < 4; ++st) {
            uint4 v = *(const uint4*)(mybnc + l31 * 72 + st * 16 + l5 * 8);
            *(uint4*)(qd + st * 512 + lane * 8) = v;
        }
    }

    // ---- V: C[s][e] (A=x,B=Wv) -> block-shared Vt[dh][s128] -> frag emit ----
    {
        bf16x8 wf[2][4];
        #pragma unroll
        for (int et = 0; et < 2; ++et)
            #pragma unroll
            for (int st = 0; st < 4; ++st)
                wf[et][st] = *(const bf16x8*)(wvb + (et * 4 + st) * 512 + lane * 8);
        #pragma unroll
        for (int et = 0; et < 2; ++et) {
            f32x16 acc = zero16();
            #pragma unroll
            for (int st = 0; st < 4; ++st)
                acc = __builtin_amdgcn_mfma_f32_32x32x16_bf16(xf[st], wf[et][st], acc, 0, 0, 0);
            const float bb = bv[h * DH_ + et * 32 + l31];
            #pragma unroll
            for (int rg = 0; rg < 4; ++rg) {
                uint2 pk;
                pk.x = rnepk(acc[rg * 4 + 0] + bb, acc[rg * 4 + 1] + bb);
                pk.y = rnepk(acc[rg * 4 + 2] + bb, acc[rg * 4 + 3] + bb);
                // Vt[dh = et*32+l31][s = w*32 + rg*8 + l5*4 + {0..3}]
                *(uint2*)(vsh + (et * 32 + l31) * 136 + w * 32 + rg * 8 + l5 * 4) = pk;
            }
        }
        __syncthreads();
        #pragma unroll
        for (int i = 0; i < 4; ++i) {
            const int c = w * 4 + i;                 // 16 chunks: [ktl][dht][st]
            const int ktl = c >> 3, dht = (c >> 2) & 1, st = c & 3;
            uint4 v = *(const uint4*)(vsh + (dht * 32 + l31) * 136 + ktl * 64 + st * 16 + l5 * 8);
            *(uint4*)(Vf + (((size_t)(bh * 32 + sblk * 2 + ktl)) * 2 + dht) * 2048
                      + st * 512 + lane * 8) = v;
        }
    }
}

// ---------------------------------------------------------------------------
// Kernel 2: flash (unchanged from R5/R6, validated).
// ---------------------------------------------------------------------------
__global__ __launch_bounds__(512, 4)
void flash_mfma(const ushort* __restrict__ Qf, const ushort* __restrict__ Kf,
                const ushort* __restrict__ Vf, float* __restrict__ out)
{
    const int bh = blockIdx.x, qblk = blockIdx.y;
    const int b = bh >> 3, h = bh & 7;
    const int tid = threadIdx.x;
    const int w = tid >> 6, lane = tid & 63, l31 = lane & 31, l5 = lane >> 5;
    const int qi = w & 3, p = w >> 2;    // q-tile within block, K-parity

    // dbuf: buf s at s*16384 ush (32KB): [Kp0 4096][Vp0 4096][Kp1 4096][Vp1 4096]
    // epilogue overlays: 4 x (32q x 68 f32) + 128 lsum = 35328 B
    __shared__ __align__(16) ushort lds_u[32768];    // 65536 B

    // staging role of wave w: region w (4 KB = 4 chunks of 1 KB)
    const ushort* gsrc = (((w >> 1) & 1) ? Vf : Kf)
                         + (size_t)bh * 32 * 4096 + (size_t)(w & 1) * 2048;
    const int stp = w >> 2;              // parity of the tile this wave stages
    ushort* const stdst0 = lds_u + w * 2048;

    // ---- prologue: DMA step-0 tiles (kt = stp) into buf0 ----
    {
        const ushort* gb = gsrc + (size_t)stp * 4096;
        #pragma unroll
        for (int i = 0; i < 4; ++i)
            dma16(gb + i * 512 + lane * 8, stdst0 + i * 512);
    }

    // ---- Q B-frags (coalesced from Qf), tile qblk*4 + qi ----
    bf16x8 qf[4];
    #pragma unroll
    for (int st = 0; st < 4; ++st)
        qf[st] = *(const bf16x8*)(Qf + ((size_t)(bh * 64 + qblk * 4 + qi)) * 2048
                                  + st * 512 + lane * 8);

    const f32x16 fz = zero16();          // shared zero C-in (no per-step movs)
    f32x16 O[2];                         // [dht], O^T cols q = l31
    O[0] = fz; O[1] = fz;
    float lsum = 0.f;

    for (int step = 0; step < 16; ++step) {
        __syncthreads();                 // drains DMAs for buf[cur]
        const ushort* cbuf = lds_u + (step & 1) * 16384;
        if (step < 15) {                 // DMA tile kt=2*(step+1)+stp into other buf
            const ushort* gb = gsrc + (size_t)(2 * (step + 1) + stp) * 4096;
            ushort* ld = lds_u + ((step + 1) & 1) * 16384 + w * 2048;
            #pragma unroll
            for (int i = 0; i < 4; ++i)
                dma16(gb + i * 512 + lane * 8, ld + i * 512);
        }
        const ushort* kreg = cbuf + p * 8192;
        const ushort* vreg = kreg + 4096;

        // ---- A: QK chain g0 ----
        bf16x8 k0 = *(const bf16x8*)(kreg + 0 * 512 + lane * 8);
        bf16x8 k1 = *(const bf16x8*)(kreg + 1 * 512 + lane * 8);
        bf16x8 k2 = *(const bf16x8*)(kreg + 2 * 512 + lane * 8);
        bf16x8 k3 = *(const bf16x8*)(kreg + 3 * 512 + lane * 8);
        __builtin_amdgcn_s_setprio(1);
        f32x16 sc0 = __builtin_amdgcn_mfma_f32_32x32x16_bf16(k0, qf[0], fz,  0, 0, 0);
        sc0        = __builtin_amdgcn_mfma_f32_32x32x16_bf16(k1, qf[1], sc0, 0, 0, 0);
        sc0        = __builtin_amdgcn_mfma_f32_32x32x16_bf16(k2, qf[2], sc0, 0, 0, 0);
        sc0        = __builtin_amdgcn_mfma_f32_32x32x16_bf16(k3, qf[3], sc0, 0, 0, 0);
        __builtin_amdgcn_s_setprio(0);

        // g1 K-frags + V st0/1 frags (independent LDS reads, fill chain gaps)
        bf16x8 g0 = *(const bf16x8*)(kreg + 4 * 512 + lane * 8);
        bf16x8 g1 = *(const bf16x8*)(kreg + 5 * 512 + lane * 8);
        bf16x8 g2 = *(const bf16x8*)(kreg + 6 * 512 + lane * 8);
        bf16x8 g3 = *(const bf16x8*)(kreg + 7 * 512 + lane * 8);
        bf16x8 va0 = *(const bf16x8*)(vreg + 0 * 512 + lane * 8);
        bf16x8 va1 = *(const bf16x8*)(vreg + 1 * 512 + lane * 8);
        bf16x8 vb0 = *(const bf16x8*)(vreg + 4 * 512 + lane * 8);
        bf16x8 vb1 = *(const bf16x8*)(vreg + 5 * 512 + lane * 8);

        // ---- B: QK chain g1 interleaved with softmax(sc0) ----
        uint pr[8];
        f32x16 sc1 = __builtin_amdgcn_mfma_f32_32x32x16_bf16(g0, qf[0], fz,  0, 0, 0);
        SMQ(sc0, 0);
        sc1        = __builtin_amdgcn_mfma_f32_32x32x16_bf16(g1, qf[1], sc1, 0, 0, 0);
        SMQ(sc0, 1);
        sc1        = __builtin_amdgcn_mfma_f32_32x32x16_bf16(g2, qf[2], sc1, 0, 0, 0);
        SMQ(sc0, 2);
        sc1        = __builtin_amdgcn_mfma_f32_32x32x16_bf16(g3, qf[3], sc1, 0, 0, 0);
        SMQ(sc0, 3);
        bf16x8 pf0, pf1;
        SWAPPF(pf0, pf1);

        // ---- C: PV st0/1 interleaved with softmax(sc1) ----
        O[0] = __builtin_amdgcn_mfma_f32_32x32x16_bf16(va0, pf0, O[0], 0, 0, 0);
        SMQ(sc1, 0);
        O[0] = __builtin_amdgcn_mfma_f32_32x32x16_bf16(va1, pf1, O[0], 0, 0, 0);
        SMQ(sc1, 1);
        O[1] = __builtin_amdgcn_mfma_f32_32x32x16_bf16(vb0, pf0, O[1], 0, 0, 0);
        SMQ(sc1, 2);
        O[1] = __builtin_amdgcn_mfma_f32_32x32x16_bf16(vb1, pf1, O[1], 0, 0, 0);
        SMQ(sc1, 3);
        bf16x8 pf2, pf3;
        SWAPPF(pf2, pf3);

        // V st2/3 frags
        bf16x8 va2 = *(const bf16x8*)(vreg + 2 * 512 + lane * 8);
        bf16x8 va3 = *(const bf16x8*)(vreg + 3 * 512 + lane * 8);
        bf16x8 vb2 = *(const bf16x8*)(vreg + 6 * 512 + lane * 8);
        bf16x8 vb3 = *(const bf16x8*)(vreg + 7 * 512 + lane * 8);

        // ---- D: PV st2/3 ----
        __builtin_amdgcn_s_setprio(1);
        O[0] = __builtin_amdgcn_mfma_f32_32x32x16_bf16(va2, pf2, O[0], 0, 0, 0);
        O[0] = __builtin_amdgcn_mfma_f32_32x32x16_bf16(va3, pf3, O[0], 0, 0, 0);
        O[1] = __builtin_amdgcn_mfma_f32_32x32x16_bf16(vb2, pf2, O[1], 0, 0, 0);
        O[1] = __builtin_amdgcn_mfma_f32_32x32x16_bf16(vb3, pf3, O[1], 0, 0, 0);
        __builtin_amdgcn_s_setprio(0);
    }

    // ---- merge parity partners (R1-validated pattern), normalize ----
    lsum += __shfl_xor(lsum, 32);

    __syncthreads();                     // all loop reads done before overlay
    float* mb = (float*)lds_u;           // 4 regions x (32q x 68 f32); lsA after
    float* reg = mb + qi * 2176;
    float* lsA = mb + 4 * 2176;          // 128 slots

    if (p == 1) {                        // odd-parity waves publish partials
        #pragma unroll
        for (int dht = 0; dht < 2; ++dht)
            #pragma unroll
            for (int rg = 0; rg < 4; ++rg) {
                f32x4 v4;
                v4[0] = O[dht][rg * 4 + 0];
                v4[1] = O[dht][rg * 4 + 1];
                v4[2] = O[dht][rg * 4 + 2];
                v4[3] = O[dht][rg * 4 + 3];
                *(f32x4*)(reg + l31 * 68 + dht * 32 + rg * 8 + l5 * 4) = v4;
            }
        if (l5 == 0) lsA[qi * 32 + l31] = lsum;
    }
    __syncthreads();
    if (p == 0) {                        // even-parity waves merge + finalize
        const float linv = 1.0f / (lsum + lsA[qi * 32 + l31]);
        #pragma unroll
        for (int dht = 0; dht < 2; ++dht)
            #pragma unroll
            for (int rg = 0; rg < 4; ++rg) {
                float* a = reg + l31 * 68 + dht * 32 + rg * 8 + l5 * 4;
                f32x4 part = *(const f32x4*)a;
                f32x4 v4;
                v4[0] = (O[dht][rg * 4 + 0] + part[0]) * linv;
                v4[1] = (O[dht][rg * 4 + 1] + part[1]) * linv;
                v4[2] = (O[dht][rg * 4 + 2] + part[2]) * linv;
                v4[3] = (O[dht][rg * 4 + 3] + part[3]) * linv;
                *(f32x4*)a = v4;
            }
    }
    __syncthreads();

    // ---- cooperative coalesced store: 128 rows x 16 chunks of 16B ----
    const int q0 = qblk * 128;
    #pragma unroll
    for (int i = 0; i < 4; ++i) {
        const int slot = tid + 512 * i;
        const int r = slot >> 4, c = slot & 15;
        f32x4 v = *(const f32x4*)(mb + (r >> 5) * 2176 + (r & 31) * 68 + c * 4);
        *(f32x4*)(out + ((size_t)(b * S_ + q0 + r)) * D_ + h * DH_ + c * 4) = v;
    }
}

extern "C" void kernel_launch(void* const* d_in, const int* in_sizes, int n_in,
                              void* d_out, int out_size, void* d_ws, size_t ws_size,
                              hipStream_t stream) {
    const float* x  = (const float*)d_in[0];
    const float* Wq = (const float*)d_in[1];
    const float* bq = (const float*)d_in[2];
    const float* Wk = (const float*)d_in[3];
    const float* bk = (const float*)d_in[4];
    const float* Wv = (const float*)d_in[5];
    const float* bv = (const float*)d_in[6];
    float* outp = (float*)d_out;

    ushort* Qf  = (ushort*)d_ws;                       // frag-linear, 8 MB
    ushort* Kf  = Qf + (size_t)BH_ * S_ * DH_;         // 8 MB
    ushort* Vf  = Kf + (size_t)BH_ * S_ * DH_;         // 8 MB
    ushort* Wfb = Vf + (size_t)BH_ * S_ * DH_;         // 192 KB bf16 W frags

    prep_w<<<dim3(24), 256, 0, stream>>>(Wq, Wk, Wv, Wfb);
    qkv_mfma<<<dim3(BH_, S_ / 128), 256, 0, stream>>>(x, bq, bk, bv, Wfb,
                                                      Qf, Kf, Vf);
    flash_mfma<<<dim3(BH_, 16), 512, 0, stream>>>(Qf, Kf, Vf, outp);
}

// Round 8
// 123.896 us; speedup vs baseline: 1.0172x; 1.0029x over previous
//
#include <hip/hip_runtime.h>
#include <math.h>

#define B_ 4
#define S_ 2048
#define D_ 512
#define H_ 8
#define DH_ 64
#define BH_ (B_*H_)
#define SCALE 0.1803368801111243f   // log2(e)/sqrt(64)

typedef __attribute__((ext_vector_type(4)))  float f32x4;
typedef __attribute__((ext_vector_type(16))) float f32x16;
typedef __attribute__((ext_vector_type(8)))  short bf16x8;
typedef __attribute__((ext_vector_type(4)))  uint  u32x4;

__device__ inline uint rnepk(float a, float b) {
    uint ua = __builtin_bit_cast(uint, a), ub = __builtin_bit_cast(uint, b);
    ua += 0x7FFFu + ((ua >> 16) & 1u);
    ub += 0x7FFFu + ((ub >> 16) & 1u);
    return (ua >> 16) | (ub & 0xFFFF0000u);
}
__device__ inline uint truncpk(float lo, float hi) {   // 1 v_perm_b32
    return __builtin_amdgcn_perm(__builtin_bit_cast(uint, hi),
                                 __builtin_bit_cast(uint, lo), 0x07060302u);
}
__device__ inline f32x16 zero16() {
    f32x16 z;
    #pragma unroll
    for (int i = 0; i < 16; ++i) z[i] = 0.f;
    return z;
}
__device__ inline bf16x8 pack8(f32x4 a, f32x4 c) {
    u32x4 u;
    u.x = rnepk(a[0], a[1]); u.y = rnepk(a[2], a[3]);
    u.z = rnepk(c[0], c[1]); u.w = rnepk(c[2], c[3]);
    return __builtin_bit_cast(bf16x8, u);
}

// (lane,lane^32) quad exchange (validated)
#if __has_builtin(__builtin_amdgcn_permlane32_swap)
__device__ inline void lane32swap(uint& a, uint& b) {
    typedef __attribute__((ext_vector_type(2))) uint u32x2;
    u32x2 r = __builtin_amdgcn_permlane32_swap(a, b, false, false);
    a = r.x; b = r.y;
}
#else
__device__ inline void lane32swap(uint& a, uint& b) {
    const int l5 = (threadIdx.x & 63) >> 5;
    uint send = l5 ? a : b;
    uint recv = __shfl_xor(send, 32);
    uint an = l5 ? recv : a;
    uint bn = l5 ? b : recv;
    a = an; b = bn;
}
#endif

// async global->LDS DMA, 16B/lane: LDS dest = wave-uniform base + lane*16
__device__ inline void dma16(const ushort* g, ushort* l) {
    __builtin_amdgcn_global_load_lds(
        (const __attribute__((address_space(1))) unsigned int*)g,
        (__attribute__((address_space(3))) unsigned int*)l, 16, 0, 0);
}

// softmax quarter for row-group RG of score block SC (order-preserving)
#define SMQ(SC, RG) do {                                                     \
    float p0_ = __builtin_amdgcn_exp2f(SC[RG * 4 + 0]);                      \
    float p1_ = __builtin_amdgcn_exp2f(SC[RG * 4 + 1]);                      \
    float p2_ = __builtin_amdgcn_exp2f(SC[RG * 4 + 2]);                      \
    float p3_ = __builtin_amdgcn_exp2f(SC[RG * 4 + 3]);                      \
    lsum += (p0_ + p1_) + (p2_ + p3_);                                       \
    pr[2 * RG + 0] = truncpk(p0_, p1_);                                      \
    pr[2 * RG + 1] = truncpk(p2_, p3_);                                      \
} while (0)

// quad-exchange pr[] -> two PV A-fragments (identical to validated pp-loop)
#define SWAPPF(PF0, PF1) do {                                                \
    lane32swap(pr[0], pr[2]); lane32swap(pr[1], pr[3]);                      \
    lane32swap(pr[4], pr[6]); lane32swap(pr[5], pr[7]);                      \
    u32x4 u0_; u0_.x = pr[0]; u0_.y = pr[1]; u0_.z = pr[2]; u0_.w = pr[3];   \
    u32x4 u1_; u1_.x = pr[4]; u1_.y = pr[5]; u1_.z = pr[6]; u1_.w = pr[7];   \
    PF0 = __builtin_bit_cast(bf16x8, u0_);                                   \
    PF1 = __builtin_bit_cast(bf16x8, u1_);                                   \
} while (0)

// ---------------------------------------------------------------------------
// Kernel 0: weight prep (unchanged, validated). Wq/Wk/Wv f32 -> frag bf16.
// Wf[((proj*8+h)*8 + (et*4+st))*512 + lane*8], proj 0=Q 1=K 2=V.
// ---------------------------------------------------------------------------
__global__ __launch_bounds__(256)
void prep_w(const float* __restrict__ Wq, const float* __restrict__ Wk,
            const float* __restrict__ Wv, ushort* __restrict__ Wf)
{
    const int pb = blockIdx.x;                 // 0..23 = proj*8 + h
    const int proj = pb >> 3, h = pb & 7;
    const float* W = (proj == 0 ? Wq : proj == 1 ? Wk : Wv) + h * DH_ * DH_;
    #pragma unroll
    for (int it = 0; it < 2; ++it) {
        const int slot = threadIdx.x + it * 256;   // 512 lane-slots
        const int c = slot >> 6, lane = slot & 63;
        const int l31 = lane & 31, l5 = lane >> 5;
        const int et = c >> 2, st = c & 3;
        const float* wr = W + (et * 32 + l31) * DH_ + st * 16 + l5 * 8;
        bf16x8 v = pack8(*(const f32x4*)wr, *(const f32x4*)(wr + 4));
        *(bf16x8*)(Wf + ((size_t)pb * 8 + c) * 512 + lane * 8) = v;
    }
}

// ---------------------------------------------------------------------------
// Kernel 1: QKV projection, PROJECTION-SPLIT. CHANGE vs R7: qkv was grid-
// limited to 2 waves/SIMD (2048 wave-jobs over 1024 SIMDs) with a long
// serial chain per wave (all three projections). Now each block does ONE
// projection (blockIdx.z: 0=Q 1=K 2=V) for 64 rows with 2 waves (128 thr):
// grid 32x32x3 = 3072 blocks, LDS 17.4 KB -> ~9 blocks/CU -> ~4.5 waves/SIMD
// with 3x shorter chains. All index math transplanted from the validated
// kernel: bounce l31*72 layout, qt=sblk*2+w, kt=sblk/g=w, vsh relabeled
// 128s->64s (stride 136->68, drop ktl). Bit-identical arithmetic.
// ---------------------------------------------------------------------------
__global__ __launch_bounds__(128, 4)
void qkv_mfma(const float* __restrict__ x,
              const float* __restrict__ bq, const float* __restrict__ bk,
              const float* __restrict__ bv, const ushort* __restrict__ Wf,
              ushort* __restrict__ Qf, ushort* __restrict__ Kf,
              ushort* __restrict__ Vf)
{
    const int bh = blockIdx.x, b = bh >> 3, h = bh & 7;
    const int sblk = blockIdx.y, s0 = sblk * 64;
    const int proj = blockIdx.z;
    const int tid = threadIdx.x;
    const int w = tid >> 6, lane = tid & 63, l31 = lane & 31, l5 = lane >> 5;

    // union: xs 64x68 f32 = 17408 B, dead after xf build; then
    //   Q/K: bnc 2 x 2560 ush (10240 B) | V: vsh 64x68 ush (8704 B)
    __shared__ __align__(16) ushort smem_u[8704];
    float* xs = (float*)smem_u;

    // ---- coalesced x stage: 8 passes x (8 rows x 16 lanes x 16B) ----
    #pragma unroll
    for (int ps = 0; ps < 8; ++ps) {
        const int slot = tid + 128 * ps;           // 1024 slots = 64 rows x 16
        const int r = slot >> 4, c16 = slot & 15;
        f32x4 v = *(const f32x4*)(x + ((size_t)(b * S_ + s0 + r)) * D_
                                  + h * DH_ + c16 * 4);
        *(f32x4*)(xs + r * 68 + c16 * 4) = v;
    }
    __syncthreads();

    // ---- x fragments from LDS (wave w: rows w*32 .. w*32+31) ----
    const int srow = w * 32 + l31;
    bf16x8 xf[4];
    #pragma unroll
    for (int st = 0; st < 4; ++st)
        xf[st] = pack8(*(const f32x4*)(xs + srow * 68 + st * 16 + l5 * 8),
                       *(const f32x4*)(xs + srow * 68 + st * 16 + l5 * 8 + 4));
    __syncthreads();                     // xs dead; bnc/vsh may overwrite

    // ---- W fragments (pre-packed, coalesced, L1/L2-resident) ----
    const ushort* wb = Wf + ((size_t)(proj * 8 + h)) * 8 * 512;
    bf16x8 wf[2][4];
    #pragma unroll
    for (int et = 0; et < 2; ++et)
        #pragma unroll
        for (int st = 0; st < 4; ++st)
            wf[et][st] = *(const bf16x8*)(wb + (et * 4 + st) * 512 + lane * 8);

    if (proj == 0) {                     // ---- Q: C[e][s], bias+SCALE ----
        ushort* mybnc = smem_u + w * 2560;
        #pragma unroll
        for (int et = 0; et < 2; ++et) {
            f32x16 acc = zero16();
            #pragma unroll
            for (int st = 0; st < 4; ++st)
                acc = __builtin_amdgcn_mfma_f32_32x32x16_bf16(wf[et][st], xf[st], acc, 0, 0, 0);
            #pragma unroll
            for (int rg = 0; rg < 4; ++rg) {
                float4 b4 = *(const float4*)(bq + h * DH_ + et * 32 + rg * 8 + l5 * 4);
                uint2 pk;
                pk.x = rnepk((acc[rg * 4 + 0] + b4.x) * SCALE, (acc[rg * 4 + 1] + b4.y) * SCALE);
                pk.y = rnepk((acc[rg * 4 + 2] + b4.z) * SCALE, (acc[rg * 4 + 3] + b4.w) * SCALE);
                *(uint2*)(mybnc + l31 * 72 + et * 32 + rg * 8 + l5 * 4) = pk;
            }
        }
        ushort* qd = Qf + ((size_t)(bh * 64 + sblk * 2 + w)) * 2048;
        #pragma unroll
        for (int st = 0; st < 4; ++st) {
            uint4 v = *(const uint4*)(mybnc + l31 * 72 + st * 16 + l5 * 8);
            *(uint4*)(qd + st * 512 + lane * 8) = v;
        }
    } else if (proj == 1) {              // ---- K: C[e][s], bias ----
        ushort* mybnc = smem_u + w * 2560;
        #pragma unroll
        for (int et = 0; et < 2; ++et) {
            f32x16 acc = zero16();
            #pragma unroll
            for (int st = 0; st < 4; ++st)
                acc = __builtin_amdgcn_mfma_f32_32x32x16_bf16(wf[et][st], xf[st], acc, 0, 0, 0);
            #pragma unroll
            for (int rg = 0; rg < 4; ++rg) {
                float4 b4 = *(const float4*)(bk + h * DH_ + et * 32 + rg * 8 + l5 * 4);
                uint2 pk;
                pk.x = rnepk(acc[rg * 4 + 0] + b4.x, acc[rg * 4 + 1] + b4.y);
                pk.y = rnepk(acc[rg * 4 + 2] + b4.z, acc[rg * 4 + 3] + b4.w);
                *(uint2*)(mybnc + l31 * 72 + et * 32 + rg * 8 + l5 * 4) = pk;
            }
        }
        ushort* kd = Kf + (((size_t)(bh * 32 + sblk)) * 2 + w) * 2048;  // kt=sblk, g=w
        #pragma unroll
        for (int st = 0; st < 4; ++st) {
            uint4 v = *(const uint4*)(mybnc + l31 * 72 + st * 16 + l5 * 8);
            *(uint4*)(kd + st * 512 + lane * 8) = v;
        }
    } else {                             // ---- V: C[s][e] -> Vt[dh][s64] ----
        ushort* vsh = smem_u;
        #pragma unroll
        for (int et = 0; et < 2; ++et) {
            f32x16 acc = zero16();
            #pragma unroll
            for (int st = 0; st < 4; ++st)
                acc = __builtin_amdgcn_mfma_f32_32x32x16_bf16(xf[st], wf[et][st], acc, 0, 0, 0);
            const float bb = bv[h * DH_ + et * 32 + l31];
            #pragma unroll
            for (int rg = 0; rg < 4; ++rg) {
                uint2 pk;
                pk.x = rnepk(acc[rg * 4 + 0] + bb, acc[rg * 4 + 1] + bb);
                pk.y = rnepk(acc[rg * 4 + 2] + bb, acc[rg * 4 + 3] + bb);
                // Vt[dh = et*32+l31][s64 = w*32 + rg*8 + l5*4 + {0..3}]
                *(uint2*)(vsh + (et * 32 + l31) * 68 + w * 32 + rg * 8 + l5 * 4) = pk;
            }
        }
        __syncthreads();
        #pragma unroll
        for (int i = 0; i < 4; ++i) {
            const int c = w * 4 + i;                 // 8 chunks: [dht][st]
            const int dht = c >> 2, st = c & 3;
            uint4 v = *(const uint4*)(vsh + (dht * 32 + l31) * 68 + st * 16 + l5 * 8);
            *(uint4*)(Vf + (((size_t)(bh * 32 + sblk)) * 2 + dht) * 2048
                      + st * 512 + lane * 8) = v;
        }
    }
}

// ---------------------------------------------------------------------------
// Kernel 2: flash (R5/R7 validated body). CHANGE: s_setprio REMOVED —
// evidence: R0 flash (no setprio) <44.6 us; adding setprio in R1 made it
// 48.6 us (matches m190: setprio harms barrier-lockstep structures).
// ---------------------------------------------------------------------------
__global__ __launch_bounds__(512, 4)
void flash_mfma(const ushort* __restrict__ Qf, const ushort* __restrict__ Kf,
                const ushort* __restrict__ Vf, float* __restrict__ out)
{
    const int bh = blockIdx.x, qblk = blockIdx.y;
    const int b = bh >> 3, h = bh & 7;
    const int tid = threadIdx.x;
    const int w = tid >> 6, lane = tid & 63, l31 = lane & 31, l5 = lane >> 5;
    const int qi = w & 3, p = w >> 2;    // q-tile within block, K-parity

    // dbuf: buf s at s*16384 ush (32KB): [Kp0 4096][Vp0 4096][Kp1 4096][Vp1 4096]
    // epilogue overlays: 4 x (32q x 68 f32) + 128 lsum = 35328 B
    __shared__ __align__(16) ushort lds_u[32768];    // 65536 B

    // staging role of wave w: region w (4 KB = 4 chunks of 1 KB)
    const ushort* gsrc = (((w >> 1) & 1) ? Vf : Kf)
                         + (size_t)bh * 32 * 4096 + (size_t)(w & 1) * 2048;
    const int stp = w >> 2;              // parity of the tile this wave stages
    ushort* const stdst0 = lds_u + w * 2048;

    // ---- prologue: DMA step-0 tiles (kt = stp) into buf0 ----
    {
        const ushort* gb = gsrc + (size_t)stp * 4096;
        #pragma unroll
        for (int i = 0; i < 4; ++i)
            dma16(gb + i * 512 + lane * 8, stdst0 + i * 512);
    }

    // ---- Q B-frags (coalesced from Qf), tile qblk*4 + qi ----
    bf16x8 qf[4];
    #pragma unroll
    for (int st = 0; st < 4; ++st)
        qf[st] = *(const bf16x8*)(Qf + ((size_t)(bh * 64 + qblk * 4 + qi)) * 2048
                                  + st * 512 + lane * 8);

    const f32x16 fz = zero16();          // shared zero C-in (no per-step movs)
    f32x16 O[2];                         // [dht], O^T cols q = l31
    O[0] = fz; O[1] = fz;
    float lsum = 0.f;

    for (int step = 0; step < 16; ++step) {
        __syncthreads();                 // drains DMAs for buf[cur]
        const ushort* cbuf = lds_u + (step & 1) * 16384;
        if (step < 15) {                 // DMA tile kt=2*(step+1)+stp into other buf
            const ushort* gb = gsrc + (size_t)(2 * (step + 1) + stp) * 4096;
            ushort* ld = lds_u + ((step + 1) & 1) * 16384 + w * 2048;
            #pragma unroll
            for (int i = 0; i < 4; ++i)
                dma16(gb + i * 512 + lane * 8, ld + i * 512);
        }
        const ushort* kreg = cbuf + p * 8192;
        const ushort* vreg = kreg + 4096;

        // ---- A: QK chain g0 ----
        bf16x8 k0 = *(const bf16x8*)(kreg + 0 * 512 + lane * 8);
        bf16x8 k1 = *(const bf16x8*)(kreg + 1 * 512 + lane * 8);
        bf16x8 k2 = *(const bf16x8*)(kreg + 2 * 512 + lane * 8);
        bf16x8 k3 = *(const bf16x8*)(kreg + 3 * 512 + lane * 8);
        f32x16 sc0 = __builtin_amdgcn_mfma_f32_32x32x16_bf16(k0, qf[0], fz,  0, 0, 0);
        sc0        = __builtin_amdgcn_mfma_f32_32x32x16_bf16(k1, qf[1], sc0, 0, 0, 0);
        sc0        = __builtin_amdgcn_mfma_f32_32x32x16_bf16(k2, qf[2], sc0, 0, 0, 0);
        sc0        = __builtin_amdgcn_mfma_f32_32x32x16_bf16(k3, qf[3], sc0, 0, 0, 0);

        // g1 K-frags + V st0/1 frags (independent LDS reads, fill chain gaps)
        bf16x8 g0 = *(const bf16x8*)(kreg + 4 * 512 + lane * 8);
        bf16x8 g1 = *(const bf16x8*)(kreg + 5 * 512 + lane * 8);
        bf16x8 g2 = *(const bf16x8*)(kreg + 6 * 512 + lane * 8);
        bf16x8 g3 = *(const bf16x8*)(kreg + 7 * 512 + lane * 8);
        bf16x8 va0 = *(const bf16x8*)(vreg + 0 * 512 + lane * 8);
        bf16x8 va1 = *(const bf16x8*)(vreg + 1 * 512 + lane * 8);
        bf16x8 vb0 = *(const bf16x8*)(vreg + 4 * 512 + lane * 8);
        bf16x8 vb1 = *(const bf16x8*)(vreg + 5 * 512 + lane * 8);

        // ---- B: QK chain g1 interleaved with softmax(sc0) ----
        uint pr[8];
        f32x16 sc1 = __builtin_amdgcn_mfma_f32_32x32x16_bf16(g0, qf[0], fz,  0, 0, 0);
        SMQ(sc0, 0);
        sc1        = __builtin_amdgcn_mfma_f32_32x32x16_bf16(g1, qf[1], sc1, 0, 0, 0);
        SMQ(sc0, 1);
        sc1        = __builtin_amdgcn_mfma_f32_32x32x16_bf16(g2, qf[2], sc1, 0, 0, 0);
        SMQ(sc0, 2);
        sc1        = __builtin_amdgcn_mfma_f32_32x32x16_bf16(g3, qf[3], sc1, 0, 0, 0);
        SMQ(sc0, 3);
        bf16x8 pf0, pf1;
        SWAPPF(pf0, pf1);

        // ---- C: PV st0/1 interleaved with softmax(sc1) ----
        O[0] = __builtin_amdgcn_mfma_f32_32x32x16_bf16(va0, pf0, O[0], 0, 0, 0);
        SMQ(sc1, 0);
        O[0] = __builtin_amdgcn_mfma_f32_32x32x16_bf16(va1, pf1, O[0], 0, 0, 0);
        SMQ(sc1, 1);
        O[1] = __builtin_amdgcn_mfma_f32_32x32x16_bf16(vb0, pf0, O[1], 0, 0, 0);
        SMQ(sc1, 2);
        O[1] = __builtin_amdgcn_mfma_f32_32x32x16_bf16(vb1, pf1, O[1], 0, 0, 0);
        SMQ(sc1, 3);
        bf16x8 pf2, pf3;
        SWAPPF(pf2, pf3);

        // V st2/3 frags
        bf16x8 va2 = *(const bf16x8*)(vreg + 2 * 512 + lane * 8);
        bf16x8 va3 = *(const bf16x8*)(vreg + 3 * 512 + lane * 8);
        bf16x8 vb2 = *(const bf16x8*)(vreg + 6 * 512 + lane * 8);
        bf16x8 vb3 = *(const bf16x8*)(vreg + 7 * 512 + lane * 8);

        // ---- D: PV st2/3 ----
        O[0] = __builtin_amdgcn_mfma_f32_32x32x16_bf16(va2, pf2, O[0], 0, 0, 0);
        O[0] = __builtin_amdgcn_mfma_f32_32x32x16_bf16(va3, pf3, O[0], 0, 0, 0);
        O[1] = __builtin_amdgcn_mfma_f32_32x32x16_bf16(vb2, pf2, O[1], 0, 0, 0);
        O[1] = __builtin_amdgcn_mfma_f32_32x32x16_bf16(vb3, pf3, O[1], 0, 0, 0);
    }

    // ---- merge parity partners (R1-validated pattern), normalize ----
    lsum += __shfl_xor(lsum, 32);

    __syncthreads();                     // all loop reads done before overlay
    float* mb = (float*)lds_u;           // 4 regions x (32q x 68 f32); lsA after
    float* reg = mb + qi * 2176;
    float* lsA = mb + 4 * 2176;          // 128 slots

    if (p == 1) {                        // odd-parity waves publish partials
        #pragma unroll
        for (int dht = 0; dht < 2; ++dht)
            #pragma unroll
            for (int rg = 0; rg < 4; ++rg) {
                f32x4 v4;
                v4[0] = O[dht][rg * 4 + 0];
                v4[1] = O[dht][rg * 4 + 1];
                v4[2] = O[dht][rg * 4 + 2];
                v4[3] = O[dht][rg * 4 + 3];
                *(f32x4*)(reg + l31 * 68 + dht * 32 + rg * 8 + l5 * 4) = v4;
            }
        if (l5 == 0) lsA[qi * 32 + l31] = lsum;
    }
    __syncthreads();
    if (p == 0) {                        // even-parity waves merge + finalize
        const float linv = 1.0f / (lsum + lsA[qi * 32 + l31]);
        #pragma unroll
        for (int dht = 0; dht < 2; ++dht)
            #pragma unroll
            for (int rg = 0; rg < 4; ++rg) {
                float* a = reg + l31 * 68 + dht * 32 + rg * 8 + l5 * 4;
                f32x4 part = *(const f32x4*)a;
                f32x4 v4;
                v4[0] = (O[dht][rg * 4 + 0] + part[0]) * linv;
                v4[1] = (O[dht][rg * 4 + 1] + part[1]) * linv;
                v4[2] = (O[dht][rg * 4 + 2] + part[2]) * linv;
                v4[3] = (O[dht][rg * 4 + 3] + part[3]) * linv;
                *(f32x4*)a = v4;
            }
    }
    __syncthreads();

    // ---- cooperative coalesced store: 128 rows x 16 chunks of 16B ----
    const int q0 = qblk * 128;
    #pragma unroll
    for (int i = 0; i < 4; ++i) {
        const int slot = tid + 512 * i;
        const int r = slot >> 4, c = slot & 15;
        f32x4 v = *(const f32x4*)(mb + (r >> 5) * 2176 + (r & 31) * 68 + c * 4);
        *(f32x4*)(out + ((size_t)(b * S_ + q0 + r)) * D_ + h * DH_ + c * 4) = v;
    }
}

extern "C" void kernel_launch(void* const* d_in, const int* in_sizes, int n_in,
                              void* d_out, int out_size, void* d_ws, size_t ws_size,
                              hipStream_t stream) {
    const float* x  = (const float*)d_in[0];
    const float* Wq = (const float*)d_in[1];
    const float* bq = (const float*)d_in[2];
    const float* Wk = (const float*)d_in[3];
    const float* bk = (const float*)d_in[4];
    const float* Wv = (const float*)d_in[5];
    const float* bv = (const float*)d_in[6];
    float* outp = (float*)d_out;

    ushort* Qf  = (ushort*)d_ws;                       // frag-linear, 8 MB
    ushort* Kf  = Qf + (size_t)BH_ * S_ * DH_;         // 8 MB
    ushort* Vf  = Kf + (size_t)BH_ * S_ * DH_;         // 8 MB
    ushort* Wfb = Vf + (size_t)BH_ * S_ * DH_;         // 192 KB bf16 W frags

    prep_w<<<dim3(24), 256, 0, stream>>>(Wq, Wk, Wv, Wfb);
    qkv_mfma<<<dim3(BH_, S_ / 64, 3), 128, 0, stream>>>(x, bq, bk, bv, Wfb,
                                                        Qf, Kf, Vf);
    flash_mfma<<<dim3(BH_, 16), 512, 0, stream>>>(Qf, Kf, Vf, outp);
}

// Round 9
// 121.518 us; speedup vs baseline: 1.0371x; 1.0196x over previous
//
#include <hip/hip_runtime.h>
#include <math.h>

#define B_ 4
#define S_ 2048
#define D_ 512
#define H_ 8
#define DH_ 64
#define BH_ (B_*H_)
#define SCALE 0.1803368801111243f   // log2(e)/sqrt(64)

typedef __attribute__((ext_vector_type(4)))  float f32x4;
typedef __attribute__((ext_vector_type(16))) float f32x16;
typedef __attribute__((ext_vector_type(8)))  short bf16x8;
typedef __attribute__((ext_vector_type(4)))  uint  u32x4;

__device__ inline uint rnepk(float a, float b) {
    uint ua = __builtin_bit_cast(uint, a), ub = __builtin_bit_cast(uint, b);
    ua += 0x7FFFu + ((ua >> 16) & 1u);
    ub += 0x7FFFu + ((ub >> 16) & 1u);
    return (ua >> 16) | (ub & 0xFFFF0000u);
}
__device__ inline uint truncpk(float lo, float hi) {   // 1 v_perm_b32
    return __builtin_amdgcn_perm(__builtin_bit_cast(uint, hi),
                                 __builtin_bit_cast(uint, lo), 0x07060302u);
}
__device__ inline f32x16 zero16() {
    f32x16 z;
    #pragma unroll
    for (int i = 0; i < 16; ++i) z[i] = 0.f;
    return z;
}
__device__ inline bf16x8 pack8(f32x4 a, f32x4 c) {
    u32x4 u;
    u.x = rnepk(a[0], a[1]); u.y = rnepk(a[2], a[3]);
    u.z = rnepk(c[0], c[1]); u.w = rnepk(c[2], c[3]);
    return __builtin_bit_cast(bf16x8, u);
}

// (lane,lane^32) quad exchange (validated)
#if __has_builtin(__builtin_amdgcn_permlane32_swap)
__device__ inline void lane32swap(uint& a, uint& b) {
    typedef __attribute__((ext_vector_type(2))) uint u32x2;
    u32x2 r = __builtin_amdgcn_permlane32_swap(a, b, false, false);
    a = r.x; b = r.y;
}
#else
__device__ inline void lane32swap(uint& a, uint& b) {
    const int l5 = (threadIdx.x & 63) >> 5;
    uint send = l5 ? a : b;
    uint recv = __shfl_xor(send, 32);
    uint an = l5 ? recv : a;
    uint bn = l5 ? b : recv;
    a = an; b = bn;
}
#endif

// async global->LDS DMA, 16B/lane: LDS dest = wave-uniform base + lane*16
__device__ inline void dma16(const ushort* g, ushort* l) {
    __builtin_amdgcn_global_load_lds(
        (const __attribute__((address_space(1))) unsigned int*)g,
        (__attribute__((address_space(3))) unsigned int*)l, 16, 0, 0);
}

// softmax quarter for row-group RG of score block SC (order-preserving)
#define SMQ(SC, RG) do {                                                     \
    float p0_ = __builtin_amdgcn_exp2f(SC[RG * 4 + 0]);                      \
    float p1_ = __builtin_amdgcn_exp2f(SC[RG * 4 + 1]);                      \
    float p2_ = __builtin_amdgcn_exp2f(SC[RG * 4 + 2]);                      \
    float p3_ = __builtin_amdgcn_exp2f(SC[RG * 4 + 3]);                      \
    lsum += (p0_ + p1_) + (p2_ + p3_);                                       \
    pr[2 * RG + 0] = truncpk(p0_, p1_);                                      \
    pr[2 * RG + 1] = truncpk(p2_, p3_);                                      \
} while (0)

// quad-exchange pr[] -> two PV A-fragments (identical to validated pp-loop)
#define SWAPPF(PF0, PF1) do {                                                \
    lane32swap(pr[0], pr[2]); lane32swap(pr[1], pr[3]);                      \
    lane32swap(pr[4], pr[6]); lane32swap(pr[5], pr[7]);                      \
    u32x4 u0_; u0_.x = pr[0]; u0_.y = pr[1]; u0_.z = pr[2]; u0_.w = pr[3];   \
    u32x4 u1_; u1_.x = pr[4]; u1_.y = pr[5]; u1_.z = pr[6]; u1_.w = pr[7];   \
    PF0 = __builtin_bit_cast(bf16x8, u0_);                                   \
    PF1 = __builtin_bit_cast(bf16x8, u1_);                                   \
} while (0)

// ---------------------------------------------------------------------------
// Kernel 1: QKV projection, projection-split (R8 structure) with prep_w
// FUSED: each block stages its x-slice (64 rows) AND its one W matrix as
// bf16 into LDS in the same coalesced pass (rnepk applied by the stager on
// the identical f32 values -> all fragments bit-identical to the prep_w
// path). Fragments are then plain 16B LDS reads — no per-wave pack VALU,
// no global Wf round-trip, one fewer kernel launch. LDS 18.4 KB.
// grid (32 bh, 32 sblk, 3 proj), 128 thr.
// ---------------------------------------------------------------------------
__global__ __launch_bounds__(128, 4)
void qkv_mfma(const float* __restrict__ x,
              const float* __restrict__ Wq, const float* __restrict__ Wk,
              const float* __restrict__ Wv,
              const float* __restrict__ bq, const float* __restrict__ bk,
              const float* __restrict__ bv,
              ushort* __restrict__ Qf, ushort* __restrict__ Kf,
              ushort* __restrict__ Vf)
{
    const int bh = blockIdx.x, b = bh >> 3, h = bh & 7;
    const int sblk = blockIdx.y, s0 = sblk * 64;
    const int proj = blockIdx.z;
    const int tid = threadIdx.x;
    const int w = tid >> 6, lane = tid & 63, l31 = lane & 31, l5 = lane >> 5;

    // [xs16 64x72 ush][ws16 64x72 ush] = 18432 B; both dead after frag build,
    // then overlaid by bnc (Q/K: 2x2560 ush) or vsh (V: 64x68 ush).
    __shared__ __align__(16) ushort smem_u[9216];
    ushort* xs16 = smem_u;
    ushort* ws16 = smem_u + 4608;

    const float* Wsrc = (proj == 0 ? Wq : proj == 1 ? Wk : Wv) + h * DH_ * DH_;

    // ---- coalesced x+W stage, packed to bf16 in-flight ----
    // 512 slots each: slot -> row r = slot>>3, col-chunk c8 = slot&7 (8 f32)
    #pragma unroll
    for (int ps = 0; ps < 4; ++ps) {
        const int slot = tid + 128 * ps;
        const int r = slot >> 3, c8 = slot & 7;
        const float* xr = x + ((size_t)(b * S_ + s0 + r)) * D_ + h * DH_ + c8 * 8;
        bf16x8 vx = pack8(*(const f32x4*)xr, *(const f32x4*)(xr + 4));
        *(bf16x8*)(xs16 + r * 72 + c8 * 8) = vx;
        const float* wr = Wsrc + r * DH_ + c8 * 8;
        bf16x8 vw = pack8(*(const f32x4*)wr, *(const f32x4*)(wr + 4));
        *(bf16x8*)(ws16 + r * 72 + c8 * 8) = vw;
    }
    __syncthreads();

    // ---- fragments: plain 16B LDS reads (bit-identical to prep_w path) ----
    const int srow = w * 32 + l31;
    bf16x8 xf[4], wf[2][4];
    #pragma unroll
    for (int st = 0; st < 4; ++st)
        xf[st] = *(const bf16x8*)(xs16 + srow * 72 + st * 16 + l5 * 8);
    #pragma unroll
    for (int et = 0; et < 2; ++et)
        #pragma unroll
        for (int st = 0; st < 4; ++st)
            wf[et][st] = *(const bf16x8*)(ws16 + (et * 32 + l31) * 72 + st * 16 + l5 * 8);
    __syncthreads();                     // stage buffers dead; overlays may write

    if (proj == 0) {                     // ---- Q: C[e][s], bias+SCALE ----
        ushort* mybnc = smem_u + w * 2560;
        #pragma unroll
        for (int et = 0; et < 2; ++et) {
            f32x16 acc = zero16();
            #pragma unroll
            for (int st = 0; st < 4; ++st)
                acc = __builtin_amdgcn_mfma_f32_32x32x16_bf16(wf[et][st], xf[st], acc, 0, 0, 0);
            #pragma unroll
            for (int rg = 0; rg < 4; ++rg) {
                float4 b4 = *(const float4*)(bq + h * DH_ + et * 32 + rg * 8 + l5 * 4);
                uint2 pk;
                pk.x = rnepk((acc[rg * 4 + 0] + b4.x) * SCALE, (acc[rg * 4 + 1] + b4.y) * SCALE);
                pk.y = rnepk((acc[rg * 4 + 2] + b4.z) * SCALE, (acc[rg * 4 + 3] + b4.w) * SCALE);
                *(uint2*)(mybnc + l31 * 72 + et * 32 + rg * 8 + l5 * 4) = pk;
            }
        }
        ushort* qd = Qf + ((size_t)(bh * 64 + sblk * 2 + w)) * 2048;
        #pragma unroll
        for (int st = 0; st < 4; ++st) {
            uint4 v = *(const uint4*)(mybnc + l31 * 72 + st * 16 + l5 * 8);
            *(uint4*)(qd + st * 512 + lane * 8) = v;
        }
    } else if (proj == 1) {              // ---- K: C[e][s], bias ----
        ushort* mybnc = smem_u + w * 2560;
        #pragma unroll
        for (int et = 0; et < 2; ++et) {
            f32x16 acc = zero16();
            #pragma unroll
            for (int st = 0; st < 4; ++st)
                acc = __builtin_amdgcn_mfma_f32_32x32x16_bf16(wf[et][st], xf[st], acc, 0, 0, 0);
            #pragma unroll
            for (int rg = 0; rg < 4; ++rg) {
                float4 b4 = *(const float4*)(bk + h * DH_ + et * 32 + rg * 8 + l5 * 4);
                uint2 pk;
                pk.x = rnepk(acc[rg * 4 + 0] + b4.x, acc[rg * 4 + 1] + b4.y);
                pk.y = rnepk(acc[rg * 4 + 2] + b4.z, acc[rg * 4 + 3] + b4.w);
                *(uint2*)(mybnc + l31 * 72 + et * 32 + rg * 8 + l5 * 4) = pk;
            }
        }
        ushort* kd = Kf + (((size_t)(bh * 32 + sblk)) * 2 + w) * 2048;  // kt=sblk, g=w
        #pragma unroll
        for (int st = 0; st < 4; ++st) {
            uint4 v = *(const uint4*)(mybnc + l31 * 72 + st * 16 + l5 * 8);
            *(uint4*)(kd + st * 512 + lane * 8) = v;
        }
    } else {                             // ---- V: C[s][e] -> Vt[dh][s64] ----
        ushort* vsh = smem_u;
        #pragma unroll
        for (int et = 0; et < 2; ++et) {
            f32x16 acc = zero16();
            #pragma unroll
            for (int st = 0; st < 4; ++st)
                acc = __builtin_amdgcn_mfma_f32_32x32x16_bf16(xf[st], wf[et][st], acc, 0, 0, 0);
            const float bb = bv[h * DH_ + et * 32 + l31];
            #pragma unroll
            for (int rg = 0; rg < 4; ++rg) {
                uint2 pk;
                pk.x = rnepk(acc[rg * 4 + 0] + bb, acc[rg * 4 + 1] + bb);
                pk.y = rnepk(acc[rg * 4 + 2] + bb, acc[rg * 4 + 3] + bb);
                // Vt[dh = et*32+l31][s64 = w*32 + rg*8 + l5*4 + {0..3}]
                *(uint2*)(vsh + (et * 32 + l31) * 68 + w * 32 + rg * 8 + l5 * 4) = pk;
            }
        }
        __syncthreads();
        #pragma unroll
        for (int i = 0; i < 4; ++i) {
            const int c = w * 4 + i;                 // 8 chunks: [dht][st]
            const int dht = c >> 2, st = c & 3;
            uint4 v = *(const uint4*)(vsh + (dht * 32 + l31) * 68 + st * 16 + l5 * 8);
            *(uint4*)(Vf + (((size_t)(bh * 32 + sblk)) * 2 + dht) * 2048
                      + st * 512 + lane * 8) = v;
        }
    }
}

// ---------------------------------------------------------------------------
// Kernel 2: flash (unchanged from R8, validated).
// ---------------------------------------------------------------------------
__global__ __launch_bounds__(512, 4)
void flash_mfma(const ushort* __restrict__ Qf, const ushort* __restrict__ Kf,
                const ushort* __restrict__ Vf, float* __restrict__ out)
{
    const int bh = blockIdx.x, qblk = blockIdx.y;
    const int b = bh >> 3, h = bh & 7;
    const int tid = threadIdx.x;
    const int w = tid >> 6, lane = tid & 63, l31 = lane & 31, l5 = lane >> 5;
    const int qi = w & 3, p = w >> 2;    // q-tile within block, K-parity

    // dbuf: buf s at s*16384 ush (32KB): [Kp0 4096][Vp0 4096][Kp1 4096][Vp1 4096]
    // epilogue overlays: 4 x (32q x 68 f32) + 128 lsum = 35328 B
    __shared__ __align__(16) ushort lds_u[32768];    // 65536 B

    // staging role of wave w: region w (4 KB = 4 chunks of 1 KB)
    const ushort* gsrc = (((w >> 1) & 1) ? Vf : Kf)
                         + (size_t)bh * 32 * 4096 + (size_t)(w & 1) * 2048;
    const int stp = w >> 2;              // parity of the tile this wave stages
    ushort* const stdst0 = lds_u + w * 2048;

    // ---- prologue: DMA step-0 tiles (kt = stp) into buf0 ----
    {
        const ushort* gb = gsrc + (size_t)stp * 4096;
        #pragma unroll
        for (int i = 0; i < 4; ++i)
            dma16(gb + i * 512 + lane * 8, stdst0 + i * 512);
    }

    // ---- Q B-frags (coalesced from Qf), tile qblk*4 + qi ----
    bf16x8 qf[4];
    #pragma unroll
    for (int st = 0; st < 4; ++st)
        qf[st] = *(const bf16x8*)(Qf + ((size_t)(bh * 64 + qblk * 4 + qi)) * 2048
                                  + st * 512 + lane * 8);

    const f32x16 fz = zero16();          // shared zero C-in (no per-step movs)
    f32x16 O[2];                         // [dht], O^T cols q = l31
    O[0] = fz; O[1] = fz;
    float lsum = 0.f;

    for (int step = 0; step < 16; ++step) {
        __syncthreads();                 // drains DMAs for buf[cur]
        const ushort* cbuf = lds_u + (step & 1) * 16384;
        if (step < 15) {                 // DMA tile kt=2*(step+1)+stp into other buf
            const ushort* gb = gsrc + (size_t)(2 * (step + 1) + stp) * 4096;
            ushort* ld = lds_u + ((step + 1) & 1) * 16384 + w * 2048;
            #pragma unroll
            for (int i = 0; i < 4; ++i)
                dma16(gb + i * 512 + lane * 8, ld + i * 512);
        }
        const ushort* kreg = cbuf + p * 8192;
        const ushort* vreg = kreg + 4096;

        // ---- A: QK chain g0 ----
        bf16x8 k0 = *(const bf16x8*)(kreg + 0 * 512 + lane * 8);
        bf16x8 k1 = *(const bf16x8*)(kreg + 1 * 512 + lane * 8);
        bf16x8 k2 = *(const bf16x8*)(kreg + 2 * 512 + lane * 8);
        bf16x8 k3 = *(const bf16x8*)(kreg + 3 * 512 + lane * 8);
        f32x16 sc0 = __builtin_amdgcn_mfma_f32_32x32x16_bf16(k0, qf[0], fz,  0, 0, 0);
        sc0        = __builtin_amdgcn_mfma_f32_32x32x16_bf16(k1, qf[1], sc0, 0, 0, 0);
        sc0        = __builtin_amdgcn_mfma_f32_32x32x16_bf16(k2, qf[2], sc0, 0, 0, 0);
        sc0        = __builtin_amdgcn_mfma_f32_32x32x16_bf16(k3, qf[3], sc0, 0, 0, 0);

        // g1 K-frags + V st0/1 frags (independent LDS reads, fill chain gaps)
        bf16x8 g0 = *(const bf16x8*)(kreg + 4 * 512 + lane * 8);
        bf16x8 g1 = *(const bf16x8*)(kreg + 5 * 512 + lane * 8);
        bf16x8 g2 = *(const bf16x8*)(kreg + 6 * 512 + lane * 8);
        bf16x8 g3 = *(const bf16x8*)(kreg + 7 * 512 + lane * 8);
        bf16x8 va0 = *(const bf16x8*)(vreg + 0 * 512 + lane * 8);
        bf16x8 va1 = *(const bf16x8*)(vreg + 1 * 512 + lane * 8);
        bf16x8 vb0 = *(const bf16x8*)(vreg + 4 * 512 + lane * 8);
        bf16x8 vb1 = *(const bf16x8*)(vreg + 5 * 512 + lane * 8);

        // ---- B: QK chain g1 interleaved with softmax(sc0) ----
        uint pr[8];
        f32x16 sc1 = __builtin_amdgcn_mfma_f32_32x32x16_bf16(g0, qf[0], fz,  0, 0, 0);
        SMQ(sc0, 0);
        sc1        = __builtin_amdgcn_mfma_f32_32x32x16_bf16(g1, qf[1], sc1, 0, 0, 0);
        SMQ(sc0, 1);
        sc1        = __builtin_amdgcn_mfma_f32_32x32x16_bf16(g2, qf[2], sc1, 0, 0, 0);
        SMQ(sc0, 2);
        sc1        = __builtin_amdgcn_mfma_f32_32x32x16_bf16(g3, qf[3], sc1, 0, 0, 0);
        SMQ(sc0, 3);
        bf16x8 pf0, pf1;
        SWAPPF(pf0, pf1);

        // ---- C: PV st0/1 interleaved with softmax(sc1) ----
        O[0] = __builtin_amdgcn_mfma_f32_32x32x16_bf16(va0, pf0, O[0], 0, 0, 0);
        SMQ(sc1, 0);
        O[0] = __builtin_amdgcn_mfma_f32_32x32x16_bf16(va1, pf1, O[0], 0, 0, 0);
        SMQ(sc1, 1);
        O[1] = __builtin_amdgcn_mfma_f32_32x32x16_bf16(vb0, pf0, O[1], 0, 0, 0);
        SMQ(sc1, 2);
        O[1] = __builtin_amdgcn_mfma_f32_32x32x16_bf16(vb1, pf1, O[1], 0, 0, 0);
        SMQ(sc1, 3);
        bf16x8 pf2, pf3;
        SWAPPF(pf2, pf3);

        // V st2/3 frags
        bf16x8 va2 = *(const bf16x8*)(vreg + 2 * 512 + lane * 8);
        bf16x8 va3 = *(const bf16x8*)(vreg + 3 * 512 + lane * 8);
        bf16x8 vb2 = *(const bf16x8*)(vreg + 6 * 512 + lane * 8);
        bf16x8 vb3 = *(const bf16x8*)(vreg + 7 * 512 + lane * 8);

        // ---- D: PV st2/3 ----
        O[0] = __builtin_amdgcn_mfma_f32_32x32x16_bf16(va2, pf2, O[0], 0, 0, 0);
        O[0] = __builtin_amdgcn_mfma_f32_32x32x16_bf16(va3, pf3, O[0], 0, 0, 0);
        O[1] = __builtin_amdgcn_mfma_f32_32x32x16_bf16(vb2, pf2, O[1], 0, 0, 0);
        O[1] = __builtin_amdgcn_mfma_f32_32x32x16_bf16(vb3, pf3, O[1], 0, 0, 0);
    }

    // ---- merge parity partners (R1-validated pattern), normalize ----
    lsum += __shfl_xor(lsum, 32);

    __syncthreads();                     // all loop reads done before overlay
    float* mb = (float*)lds_u;           // 4 regions x (32q x 68 f32); lsA after
    float* reg = mb + qi * 2176;
    float* lsA = mb + 4 * 2176;          // 128 slots

    if (p == 1) {                        // odd-parity waves publish partials
        #pragma unroll
        for (int dht = 0; dht < 2; ++dht)
            #pragma unroll
            for (int rg = 0; rg < 4; ++rg) {
                f32x4 v4;
                v4[0] = O[dht][rg * 4 + 0];
                v4[1] = O[dht][rg * 4 + 1];
                v4[2] = O[dht][rg * 4 + 2];
                v4[3] = O[dht][rg * 4 + 3];
                *(f32x4*)(reg + l31 * 68 + dht * 32 + rg * 8 + l5 * 4) = v4;
            }
        if (l5 == 0) lsA[qi * 32 + l31] = lsum;
    }
    __syncthreads();
    if (p == 0) {                        // even-parity waves merge + finalize
        const float linv = 1.0f / (lsum + lsA[qi * 32 + l31]);
        #pragma unroll
        for (int dht = 0; dht < 2; ++dht)
            #pragma unroll
            for (int rg = 0; rg < 4; ++rg) {
                float* a = reg + l31 * 68 + dht * 32 + rg * 8 + l5 * 4;
                f32x4 part = *(const f32x4*)a;
                f32x4 v4;
                v4[0] = (O[dht][rg * 4 + 0] + part[0]) * linv;
                v4[1] = (O[dht][rg * 4 + 1] + part[1]) * linv;
                v4[2] = (O[dht][rg * 4 + 2] + part[2]) * linv;
                v4[3] = (O[dht][rg * 4 + 3] + part[3]) * linv;
                *(f32x4*)a = v4;
            }
    }
    __syncthreads();

    // ---- cooperative coalesced store: 128 rows x 16 chunks of 16B ----
    const int q0 = qblk * 128;
    #pragma unroll
    for (int i = 0; i < 4; ++i) {
        const int slot = tid + 512 * i;
        const int r = slot >> 4, c = slot & 15;
        f32x4 v = *(const f32x4*)(mb + (r >> 5) * 2176 + (r & 31) * 68 + c * 4);
        *(f32x4*)(out + ((size_t)(b * S_ + q0 + r)) * D_ + h * DH_ + c * 4) = v;
    }
}

extern "C" void kernel_launch(void* const* d_in, const int* in_sizes, int n_in,
                              void* d_out, int out_size, void* d_ws, size_t ws_size,
                              hipStream_t stream) {
    const float* x  = (const float*)d_in[0];
    const float* Wq = (const float*)d_in[1];
    const float* bq = (const float*)d_in[2];
    const float* Wk = (const float*)d_in[3];
    const float* bk = (const float*)d_in[4];
    const float* Wv = (const float*)d_in[5];
    const float* bv = (const float*)d_in[6];
    float* outp = (float*)d_out;

    ushort* Qf  = (ushort*)d_ws;                       // frag-linear, 8 MB
    ushort* Kf  = Qf + (size_t)BH_ * S_ * DH_;         // 8 MB
    ushort* Vf  = Kf + (size_t)BH_ * S_ * DH_;         // 8 MB

    qkv_mfma<<<dim3(BH_, S_ / 64, 3), 128, 0, stream>>>(x, Wq, Wk, Wv,
                                                        bq, bk, bv,
                                                        Qf, Kf, Vf);
    flash_mfma<<<dim3(BH_, 16), 512, 0, stream>>>(Qf, Kf, Vf, outp);
}